// Round 1
// baseline (3319.151 us; speedup 1.0000x reference)
//
#include <hip/hip_runtime.h>
#include <math.h>

// ---------------------------------------------------------------------------
// HDMOEM: MoE diffusion block forward. Round 0: correctness-first f32 port.
// B=4, C=4, H=W=64, E=4 experts per path, TOPK=2.
// Router masks (d_in[3], d_in[4]) are all-True in this problem and ignored.
// Experts with router weight == 0.0 are skipped (exactly equivalent to the
// dense einsum: 0 * anything == 0).
// ---------------------------------------------------------------------------

#define DEV_INLINE __device__ __forceinline__

DEV_INLINE float mp_silu_f(float x) {
    // silu(x)/0.596 = x / ((1+e^-x) * 0.596)
    return x / ((1.f + __expf(-x)) * 0.596f);
}

// ---- per-row magnitude-preserving scale: 1/(sqrt(mean(w^2)+1e-8)*sqrt(fan))
__global__ void rowscale_kernel(const float* __restrict__ w, float* __restrict__ out, int fanin) {
    int r = blockIdx.x;
    const float* p = w + (size_t)r * fanin;
    float s = 0.f;
    for (int i = threadIdx.x; i < fanin; i += 256) { float v = p[i]; s += v * v; }
    __shared__ float red[256];
    red[threadIdx.x] = s;
    __syncthreads();
    for (int st = 128; st > 0; st >>= 1) {
        if (threadIdx.x < st) red[threadIdx.x] += red[threadIdx.x + st];
        __syncthreads();
    }
    if (threadIdx.x == 0) {
        float mean = red[0] / (float)fanin;
        out[r] = 1.f / sqrtf((mean + 1e-8f) * (float)fanin);
    }
}

// ---- Fourier time embedding: femb[b,j] = sqrt(2)*cos(2pi*(t[b]*f[j]+p[j]))
__global__ void femb_kernel(const float* __restrict__ tv, const float* __restrict__ fr,
                            const float* __restrict__ ph, float* __restrict__ femb) {
    int i = blockIdx.x * 256 + threadIdx.x;
    if (i >= 4 * 256) return;
    int b = i >> 8, j = i & 255;
    femb[i] = 1.41421356237f * cosf(6.28318530717958647f * (tv[b] * fr[j] + ph[j]));
}

// ---- generic tiled linear: out[M,N] = epilogue(A[M,K] @ (W[N,K]*wsc)^T)
// epilogue: val=dot*wsc[n]; +pos[s,n]; *(1+cond[b,n]); ACT; (val+res)*outscale
template <int ACT>
__global__ void linear_kernel(const float* __restrict__ A, const float* __restrict__ W,
                              const float* __restrict__ wsc,
                              const float* __restrict__ pos,   // [mPerBatch,N] or null
                              const float* __restrict__ cond,  // [B,N] or null
                              const float* __restrict__ res,   // [M,N] or null
                              float outscale,
                              const float* __restrict__ gate, int gateStride, int mPerBatch,
                              float* __restrict__ out, int M, int N, int K) {
    int bm = blockIdx.y * 32, bn = blockIdx.x * 32;
    if (gate && gate[(bm / mPerBatch) * gateStride] == 0.f) return;
    __shared__ float As[32][33], Bs[32][33];
    int tid = threadIdx.x;
    int ty = tid >> 4, tx = tid & 15;
    float acc00 = 0.f, acc01 = 0.f, acc10 = 0.f, acc11 = 0.f;
    for (int k0 = 0; k0 < K; k0 += 32) {
#pragma unroll
        for (int i = 0; i < 4; ++i) {
            int idx = tid + i * 256;
            int r = idx >> 5, c = idx & 31;
            int m = bm + r;
            As[r][c] = (m < M) ? A[(size_t)m * K + k0 + c] : 0.f;
            Bs[r][c] = W[(size_t)(bn + r) * K + k0 + c];  // N,K multiples of 32
        }
        __syncthreads();
#pragma unroll
        for (int kk = 0; kk < 32; ++kk) {
            float a0 = As[ty][kk], a1 = As[ty + 16][kk];
            float b0 = Bs[tx][kk], b1 = Bs[tx + 16][kk];
            acc00 += a0 * b0; acc01 += a0 * b1;
            acc10 += a1 * b0; acc11 += a1 * b1;
        }
        __syncthreads();
    }
    float accs[2][2] = {{acc00, acc01}, {acc10, acc11}};
#pragma unroll
    for (int im = 0; im < 2; ++im) {
        int m = bm + ty + im * 16;
        if (m >= M) continue;
        int bb = m / mPerBatch;
#pragma unroll
        for (int jn = 0; jn < 2; ++jn) {
            int n = bn + tx + jn * 16;
            float val = accs[im][jn] * wsc[n];
            if (pos) val += pos[(size_t)(m % mPerBatch) * N + n];
            if (cond) val *= (1.f + cond[(size_t)bb * N + n]);
            if (ACT == 1) val = mp_silu_f(val);
            if (res) val = (val + res[(size_t)m * N + n]) * outscale;
            out[(size_t)m * N + n] = val;
        }
    }
}

// ---- scale router: scale2[b,2] = 2*softmax(linear(temb,w_scale)/zeta)
__global__ void scale_kernel(const float* __restrict__ temb, const float* __restrict__ w,
                             const float* __restrict__ wsc, const float* __restrict__ zeta,
                             float* __restrict__ scale2) {
    __shared__ float lg[8];
    int t = threadIdx.x;
    if (t < 8) {
        int b = t >> 1, o = t & 1;
        float s = 0.f;
        for (int k = 0; k < 512; ++k) s += temb[b * 512 + k] * w[o * 512 + k];
        lg[t] = s * wsc[o] / zeta[0];
    }
    __syncthreads();
    if (t < 4) {
        float a = lg[t * 2], b2 = lg[t * 2 + 1];
        float m = fmaxf(a, b2);
        float e0 = expf(a - m), e1 = expf(b2 - m);
        float inv = 2.f / (e0 + e1);
        scale2[t * 2] = e0 * inv;
        scale2[t * 2 + 1] = e1 * inv;
    }
}

// ---- mean over H*W of x per (b,c)
__global__ void meanx_kernel(const float* __restrict__ x, float* __restrict__ mean_x) {
    int bc = blockIdx.x;
    float s = 0.f;
    for (int i = threadIdx.x; i < 4096; i += 256) s += x[bc * 4096 + i];
    __shared__ float red[256];
    red[threadIdx.x] = s;
    __syncthreads();
    for (int st = 128; st > 0; st >>= 1) {
        if (threadIdx.x < st) red[threadIdx.x] += red[threadIdx.x + st];
        __syncthreads();
    }
    if (threadIdx.x == 0) mean_x[bc] = red[0] * (1.f / 4096.f);
}

// ---- both routers: logits, softmax, top-2 renormalized weights + probs out
__global__ void router_kernel(const float* __restrict__ mean_x, const float* __restrict__ scale2,
                              const float* __restrict__ temb,
                              const float* __restrict__ wu, const float* __restrict__ su,
                              const float* __restrict__ wv, const float* __restrict__ sv,
                              const float* __restrict__ zeta,
                              float* __restrict__ rwu, float* __restrict__ rwv,
                              float* __restrict__ probs_out) {
    __shared__ float lg[2][4][4];
    int t = threadIdx.x;
    if (t < 32) {
        int r = t >> 4, b = (t >> 2) & 3, e = t & 3;
        const float* w = (r == 0) ? wu : wv;
        const float* sc = (r == 0) ? su : sv;
        float ps = scale2[b * 2 + (r == 0 ? 1 : 0)];  // unet uses scale[:,1], vit scale[:,0]
        float acc = 0.f;
        for (int c = 0; c < 4; ++c) acc += mean_x[b * 4 + c] * ps * w[e * 516 + c];
        for (int j = 0; j < 512; ++j) acc += temb[b * 512 + j] * w[e * 516 + 4 + j];
        lg[r][b][e] = acc * sc[e] / zeta[0];
    }
    __syncthreads();
    if (t < 8) {
        int r = t >> 2, b = t & 3;
        float p[4];
        float mx = -1e30f;
        for (int e = 0; e < 4; ++e) mx = fmaxf(mx, lg[r][b][e]);
        float sum = 0.f;
        for (int e = 0; e < 4; ++e) { p[e] = expf(lg[r][b][e] - mx); sum += p[e]; }
        for (int e = 0; e < 4; ++e) p[e] /= sum;
        int i1 = 0;
        for (int e = 1; e < 4; ++e) if (p[e] > p[i1]) i1 = e;           // ties -> lower idx
        int i2 = -1;
        for (int e = 0; e < 4; ++e) { if (e == i1) continue; if (i2 < 0 || p[e] > p[i2]) i2 = e; }
        float inv = 1.f / (p[i1] + p[i2]);
        float* rw = (r == 0) ? rwu : rwv;
        for (int e = 0; e < 4; ++e) rw[b * 4 + e] = 0.f;
        rw[b * 4 + i1] = p[i1] * inv;
        rw[b * 4 + i2] = p[i2] * inv;
        for (int e = 0; e < 4; ++e) probs_out[r * 16 + b * 4 + e] = p[e];
    }
}

// ---- path inputs: in_vit = scale[:,0]*x, in_unet = scale[:,1]*x
__global__ void make_inputs_kernel(const float* __restrict__ x, const float* __restrict__ scale2,
                                   float* __restrict__ in_vit, float* __restrict__ in_unet) {
    int i = blockIdx.x * 256 + threadIdx.x;
    if (i >= 65536) return;
    int b = i >> 14;
    float v = x[i];
    in_vit[i] = scale2[b * 2] * v;
    in_unet[i] = scale2[b * 2 + 1] * v;
}

// ---- textp[b,f] = mean over 77 tokens
__global__ void textp_kernel(const float* __restrict__ te, float* __restrict__ tp) {
    int i = blockIdx.x * 256 + threadIdx.x;
    if (i >= 4 * 768) return;
    int b = i / 768, f = i % 768;
    float s = 0.f;
    for (int t = 0; t < 77; ++t) s += te[(size_t)(b * 77 + t) * 768 + f];
    tp[i] = s * (1.f / 77.f);
}

// ---- patchify in_vit (p=8) -> patchtok[b, s(=gy*8+gx), f(=c*64+py*8+px)]
__global__ void patchify_kernel(const float* __restrict__ in_vit, float* __restrict__ pt) {
    int i = blockIdx.x * 256 + threadIdx.x;
    if (i >= 65536) return;
    int b = i >> 14;
    int r = i & 16383;
    int s = r >> 8, f = r & 255;
    int c = f >> 6, py = (f >> 3) & 7, px = f & 7;
    int gy = s >> 3, gx = s & 7;
    pt[i] = in_vit[((b * 4 + c) * 64 + gy * 8 + py) * 64 + gx * 8 + px];
}

// ---- 3x3 SAME conv, H=W=64. LDS input tile 16x16(+halo), OC_PER chans/thread.
// Weight addresses are blockIdx-uniform -> scalar loads.
template <int IC_CHUNK, int OC_PER, int ACT, bool TMOD, bool ACCGAIN>
__global__ void conv3x3_kernel(const float* __restrict__ in, int IC,
                               const float* __restrict__ w,     // [OC,IC,3,3]
                               const float* __restrict__ wsc,   // [OC]
                               const float* __restrict__ tmod,  // [B,OC] or null
                               const float* __restrict__ gate, int gateStride,
                               float* __restrict__ out, int OC) {
    int b = blockIdx.z;
    float g = 1.f;
    if (gate) { g = gate[b * gateStride]; if (g == 0.f) return; }
    int tileIdx = blockIdx.x;
    int ty0 = (tileIdx >> 2) * 16, tx0 = (tileIdx & 3) * 16;
    int oc0 = blockIdx.y * OC_PER;
    int lty = threadIdx.x >> 4, ltx = threadIdx.x & 15;
    int y = ty0 + lty, x = tx0 + ltx;
    __shared__ float tile[IC_CHUNK][18][18];
    float acc[OC_PER];
#pragma unroll
    for (int o = 0; o < OC_PER; ++o) acc[o] = 0.f;
    for (int c0 = 0; c0 < IC; c0 += IC_CHUNK) {
        for (int i = threadIdx.x; i < IC_CHUNK * 18 * 18; i += 256) {
            int ic = i / (18 * 18);
            int rr = (i / 18) % 18, cc = i % 18;
            int gy = ty0 - 1 + rr, gx = tx0 - 1 + cc;
            float v = 0.f;
            if (gy >= 0 && gy < 64 && gx >= 0 && gx < 64)
                v = in[(size_t)((b * IC + c0 + ic) * 64 + gy) * 64 + gx];
            tile[ic][rr][cc] = v;
        }
        __syncthreads();
#pragma unroll
        for (int ic = 0; ic < IC_CHUNK; ++ic) {
            float win[9];
#pragma unroll
            for (int ky = 0; ky < 3; ++ky)
#pragma unroll
                for (int kx = 0; kx < 3; ++kx)
                    win[ky * 3 + kx] = tile[ic][lty + ky][ltx + kx];
            const float* wp = w + (size_t)(oc0 * IC + c0 + ic) * 9;
#pragma unroll
            for (int o = 0; o < OC_PER; ++o) {
                const float* wo = wp + (size_t)o * IC * 9;
#pragma unroll
                for (int kk = 0; kk < 9; ++kk) acc[o] += wo[kk] * win[kk];
            }
        }
        __syncthreads();
    }
#pragma unroll
    for (int o = 0; o < OC_PER; ++o) {
        int oc = oc0 + o;
        float val = acc[o] * wsc[oc];
        if (TMOD) val *= (1.f + tmod[b * OC + oc]);
        if (ACT == 1) val = mp_silu_f(val);
        size_t oidx = (size_t)((b * OC + oc) * 64 + y) * 64 + x;
        if (ACCGAIN) out[oidx] += g * val;
        else out[oidx] = val;
    }
}

// ---- ViT self-attention per (b,h): S=64, hd=64, full tiles in LDS
__global__ void vit_attn_kernel(const float* __restrict__ qkv, const float* __restrict__ gate,
                                float* __restrict__ out) {
    int b = blockIdx.x >> 3, h = blockIdx.x & 7;
    if (gate[b * 4] == 0.f) return;
    __shared__ float ks[64][65], vs[64][65], sc[64][65];
    int tid = threadIdx.x;
    for (int i = tid; i < 4096; i += 64) {
        int j = i >> 6, d = i & 63;
        ks[j][d] = qkv[(size_t)(b * 64 + j) * 1536 + 512 + h * 64 + d];
        vs[j][d] = qkv[(size_t)(b * 64 + j) * 1536 + 1024 + h * 64 + d];
    }
    float qreg[64];
#pragma unroll
    for (int d = 0; d < 64; ++d) qreg[d] = qkv[(size_t)(b * 64 + tid) * 1536 + h * 64 + d];
    __syncthreads();
    float mx = -1e30f;
    for (int j = 0; j < 64; ++j) {
        float s = 0.f;
#pragma unroll
        for (int d = 0; d < 64; ++d) s += qreg[d] * ks[j][d];
        s *= 0.125f;  // 1/sqrt(64)
        sc[tid][j] = s;
        mx = fmaxf(mx, s);
    }
    float sum = 0.f;
    for (int j = 0; j < 64; ++j) { float e = __expf(sc[tid][j] - mx); sc[tid][j] = e; sum += e; }
    float inv = 1.f / sum;
    float accd[64];
#pragma unroll
    for (int d = 0; d < 64; ++d) accd[d] = 0.f;
    for (int j = 0; j < 64; ++j) {
        float e = sc[tid][j];
#pragma unroll
        for (int d = 0; d < 64; ++d) accd[d] += e * vs[j][d];
    }
#pragma unroll
    for (int d = 0; d < 64; ++d) out[(size_t)(b * 64 + tid) * 512 + h * 64 + d] = accd[d] * inv;
}

// ---- unpatchify(linear(tok, w_unpatch)) accumulated with router gain
__global__ void unpatch_kernel(const float* __restrict__ tok, const float* __restrict__ w,
                               const float* __restrict__ wsc, const float* __restrict__ gate,
                               float* __restrict__ out) {
    int i = blockIdx.x * 256 + threadIdx.x;
    if (i >= 65536) return;
    int b = i >> 14;
    float g = gate[b * 4];
    if (g == 0.f) return;
    int c = (i >> 12) & 3, y = (i >> 6) & 63, x = i & 63;
    int f = c * 64 + (y & 7) * 8 + (x & 7);
    int s = (y >> 3) * 8 + (x >> 3);
    const float* tp = &tok[(size_t)(b * 64 + s) * 512];
    const float* wp = &w[(size_t)f * 512];
    float acc = 0.f;
    for (int em = 0; em < 512; ++em) acc += tp[em] * wp[em];
    out[i] += g * acc * wsc[f];
}

// ---- cross-attn q/k/v prep from out_unet/out_vit (layout [B,T,4], 1x1 matmuls)
__global__ void ca_qkv_kernel(const float* __restrict__ ou, const float* __restrict__ ov,
                              const float* __restrict__ wq, const float* __restrict__ sq,
                              const float* __restrict__ wk, const float* __restrict__ sk,
                              const float* __restrict__ wv, const float* __restrict__ sv,
                              float* __restrict__ q, float* __restrict__ kx, float* __restrict__ vx) {
    int i = blockIdx.x * 256 + threadIdx.x;
    if (i >= 16384) return;
    int b = i >> 12, t = i & 4095;
    float u[4], c[4];
#pragma unroll
    for (int cc = 0; cc < 4; ++cc) {
        u[cc] = ou[(size_t)(b * 4 + cc) * 4096 + t];
        c[cc] = ov[(size_t)(b * 4 + cc) * 4096 + t];
    }
#pragma unroll
    for (int o = 0; o < 4; ++o) {
        float aq = 0.f, ak = 0.f, av = 0.f;
#pragma unroll
        for (int cc = 0; cc < 4; ++cc) {
            aq += wq[o * 4 + cc] * u[cc];
            ak += wk[o * 4 + cc] * c[cc];
            av += wv[o * 4 + cc] * c[cc];
        }
        q[(size_t)(b * 4096 + t) * 4 + o] = aq * sq[o];
        kx[(size_t)(b * 4096 + t) * 4 + o] = ak * sk[o];
        vx[(size_t)(b * 4096 + t) * 4 + o] = av * sv[o];
    }
}

// ---- cross-attn flash-style: 4096 keys, d=4, online softmax
#define CA_TILE 1024
__global__ void ca_attn_kernel(const float* __restrict__ q, const float* __restrict__ k,
                               const float* __restrict__ v, float* __restrict__ o) {
    __shared__ float4 kt[CA_TILE], vt[CA_TILE];
    int b = blockIdx.x >> 6;
    int qt = ((blockIdx.x & 63) << 6) + threadIdx.x;
    const float4 qv = *(const float4*)&q[(size_t)(b * 4096 + qt) * 4];
    float m = -1e30f, l = 0.f, a0 = 0.f, a1 = 0.f, a2 = 0.f, a3 = 0.f;
    for (int t0 = 0; t0 < 4096; t0 += CA_TILE) {
        for (int j = threadIdx.x; j < CA_TILE; j += 64) {
            kt[j] = *(const float4*)&k[(size_t)(b * 4096 + t0 + j) * 4];
            vt[j] = *(const float4*)&v[(size_t)(b * 4096 + t0 + j) * 4];
        }
        __syncthreads();
        for (int j = 0; j < CA_TILE; ++j) {
            float4 kk = kt[j];
            float s = 0.5f * (qv.x * kk.x + qv.y * kk.y + qv.z * kk.z + qv.w * kk.w);  // 1/sqrt(E=4)
            float nm = fmaxf(m, s);
            float corr = __expf(m - nm);
            float e = __expf(s - nm);
            float4 vv = vt[j];
            l = l * corr + e;
            a0 = a0 * corr + e * vv.x;
            a1 = a1 * corr + e * vv.y;
            a2 = a2 * corr + e * vv.z;
            a3 = a3 * corr + e * vv.w;
            m = nm;
        }
        __syncthreads();
    }
    float inv = 1.f / l;
    float* op = &o[(size_t)(b * 4096 + qt) * 4];
    op[0] = a0 * inv; op[1] = a1 * inv; op[2] = a2 * inv; op[3] = a3 * inv;
}

// ---- cross-attn out proj + balanced residual blend -> attn_img [B,C,T]
__global__ void ca_blend_kernel(const float* __restrict__ ao, const float* __restrict__ ou,
                                const float* __restrict__ wo, const float* __restrict__ so,
                                float* __restrict__ img) {
    int i = blockIdx.x * 256 + threadIdx.x;
    if (i >= 16384) return;
    int b = i >> 12, t = i & 4095;
    float oo[4];
#pragma unroll
    for (int j = 0; j < 4; ++j) oo[j] = ao[(size_t)(b * 4096 + t) * 4 + j];
    const float inv = 1.21267812518f;  // 1/sqrt(0.2^2+0.8^2)
#pragma unroll
    for (int c = 0; c < 4; ++c) {
        float s = 0.f;
#pragma unroll
        for (int j = 0; j < 4; ++j) s += wo[c * 4 + j] * oo[j];
        s *= so[c];
        float qv = ou[(size_t)(b * 4 + c) * 4096 + t];
        img[(size_t)(b * 4 + c) * 4096 + t] = (0.2f * qv + 0.8f * s) * inv;
    }
}

// ---- gated combine: two 1x1 convs + channel softmax(2) + mix -> d_out
__global__ void gate_kernel(const float* __restrict__ ou, const float* __restrict__ ai,
                            const float* __restrict__ gw1, const float* __restrict__ s1,
                            const float* __restrict__ gw2, const float* __restrict__ s2,
                            float* __restrict__ out) {
    int i = blockIdx.x * 256 + threadIdx.x;
    if (i >= 16384) return;
    int b = i >> 12, t = i & 4095;
    float u[4], a[4];
#pragma unroll
    for (int c = 0; c < 4; ++c) {
        u[c] = ou[(size_t)(b * 4 + c) * 4096 + t];
        a[c] = ai[(size_t)(b * 4 + c) * 4096 + t];
    }
    float mvec[4];
#pragma unroll
    for (int o = 0; o < 4; ++o) {
        float s = 0.f;
#pragma unroll
        for (int c = 0; c < 4; ++c) s += gw1[o * 8 + c] * u[c] + gw1[o * 8 + 4 + c] * a[c];
        mvec[o] = mp_silu_f(s * s1[o]);
    }
    float g0 = 0.f, g1 = 0.f;
#pragma unroll
    for (int o = 0; o < 4; ++o) { g0 += gw2[o] * mvec[o]; g1 += gw2[4 + o] * mvec[o]; }
    g0 *= s2[0]; g1 *= s2[1];
    float mx = fmaxf(g0, g1);
    float e0 = expf(g0 - mx), e1 = expf(g1 - mx);
    float invd = 1.f / (e0 + e1);
    g0 = e0 * invd; g1 = e1 * invd;
#pragma unroll
    for (int c = 0; c < 4; ++c)
        out[(size_t)(b * 4 + c) * 4096 + t] = g0 * u[c] + g1 * a[c];
}

// ---------------------------------------------------------------------------
extern "C" void kernel_launch(void* const* d_in, const int* in_sizes, int n_in,
                              void* d_out, int out_size, void* d_ws, size_t ws_size,
                              hipStream_t stream) {
    (void)in_sizes; (void)n_in; (void)out_size; (void)ws_size;

    const float* x        = (const float*)d_in[0];
    const float* time_vec = (const float*)d_in[1];
    const float* text_emb = (const float*)d_in[2];
    // d_in[3], d_in[4]: router masks (all True) — ignored.
    const float* zeta     = (const float*)d_in[5];
    const float* f_freq   = (const float*)d_in[6];
    const float* f_phase  = (const float*)d_in[7];
    const float* w_f1     = (const float*)d_in[8];
    const float* w_f2     = (const float*)d_in[9];
    const float* w_scale  = (const float*)d_in[10];
    const float* w_ru     = (const float*)d_in[11];
    const float* w_rv     = (const float*)d_in[12];
    const float* uw_in    = (const float*)d_in[13];
    const float* uw_time  = (const float*)d_in[14];
    const float* uw_mid   = (const float*)d_in[15];
    const float* uw_out   = (const float*)d_in[16];
    const float* vw_patch = (const float*)d_in[17];
    const float* v_pos    = (const float*)d_in[18];
    const float* vw_qkv   = (const float*)d_in[19];
    const float* vw_proj  = (const float*)d_in[20];
    const float* vw_time  = (const float*)d_in[21];
    const float* vw_text  = (const float*)d_in[22];
    const float* vw_mlp1  = (const float*)d_in[23];
    const float* vw_mlp2  = (const float*)d_in[24];
    const float* vw_unp   = (const float*)d_in[25];
    const float* ca_wq    = (const float*)d_in[26];
    const float* ca_wk    = (const float*)d_in[27];
    const float* ca_wv    = (const float*)d_in[28];
    const float* ca_wo    = (const float*)d_in[29];
    const float* gw1      = (const float*)d_in[30];
    const float* gw2      = (const float*)d_in[31];

    float* out = (float*)d_out;

    // ---- workspace layout (floats, 4-aligned) — total ~33.7 MB
    float* Wp = (float*)d_ws;
    size_t off = 0;
    auto alloc = [&](size_t n) { float* p = Wp + off; off += (n + 3) & ~(size_t)3; return p; };

    float* s_wf1   = alloc(1024);
    float* s_wf2   = alloc(512);
    float* s_wsc   = alloc(2);
    float* s_wru   = alloc(4);
    float* s_wrv   = alloc(4);
    float* s_uwin  = alloc(768);
    float* s_uwt   = alloc(768);
    float* s_uwm   = alloc(768);
    float* s_uwo   = alloc(16);
    float* s_vwp   = alloc(2048);
    float* s_vwqkv = alloc(6144);
    float* s_vwpr  = alloc(2048);
    float* s_vwti  = alloc(2048);
    float* s_vwte  = alloc(2048);
    float* s_vwm1  = alloc(8192);
    float* s_vwm2  = alloc(2048);
    float* s_vwun  = alloc(1024);
    float* s_cawq  = alloc(4);
    float* s_cawk  = alloc(4);
    float* s_cawv  = alloc(4);
    float* s_cawo  = alloc(4);
    float* s_gw1   = alloc(4);
    float* s_gw2   = alloc(2);

    float* femb    = alloc(1024);
    float* h1      = alloc(4096);
    float* temb    = alloc(2048);
    float* scale2  = alloc(8);
    float* mean_x  = alloc(16);
    float* rwu     = alloc(16);
    float* rwv     = alloc(16);
    float* textp   = alloc(3072);
    float* tvec    = alloc(768);
    float* patchtok= alloc(65536);
    float* in_unet = alloc(65536);
    float* in_vit  = alloc(65536);
    float* out_unet= alloc(65536);
    float* out_vit = alloc(65536);   // must stay adjacent to out_unet (one memset)
    float* bufA    = alloc(3145728);
    float* bufB    = alloc(3145728);
    float* vcond   = alloc(2048);
    float* vtok    = alloc(131072);
    float* vqkv    = alloc(393216);
    float* vao     = alloc(131072);
    float* vtok2   = alloc(131072);
    float* vhid    = alloc(524288);
    float* vtok3   = alloc(131072);
    float* caq     = alloc(65536);
    float* cak     = alloc(65536);
    float* cav     = alloc(65536);
    float* cao     = alloc(65536);
    float* aimg    = alloc(65536);

    // ---- weight row scales
    auto rs = [&](const float* w, float* s, int rows, int fan) {
        rowscale_kernel<<<dim3(rows), dim3(256), 0, stream>>>(w, s, fan);
    };
    rs(w_f1, s_wf1, 1024, 256);
    rs(w_f2, s_wf2, 512, 1024);
    rs(w_scale, s_wsc, 2, 512);
    rs(w_ru, s_wru, 4, 516);
    rs(w_rv, s_wrv, 4, 516);
    rs(uw_in, s_uwin, 768, 36);
    rs(uw_time, s_uwt, 768, 512);
    rs(uw_mid, s_uwm, 768, 1728);
    rs(uw_out, s_uwo, 16, 1728);
    rs(vw_patch, s_vwp, 2048, 256);
    rs(vw_qkv, s_vwqkv, 6144, 512);
    rs(vw_proj, s_vwpr, 2048, 512);
    rs(vw_time, s_vwti, 2048, 512);
    rs(vw_text, s_vwte, 2048, 768);
    rs(vw_mlp1, s_vwm1, 8192, 512);
    rs(vw_mlp2, s_vwm2, 2048, 2048);
    rs(vw_unp, s_vwun, 1024, 512);
    rs(ca_wq, s_cawq, 4, 4);
    rs(ca_wk, s_cawk, 4, 4);
    rs(ca_wv, s_cawv, 4, 4);
    rs(ca_wo, s_cawo, 4, 4);
    rs(gw1, s_gw1, 4, 8);
    rs(gw2, s_gw2, 2, 4);

    // zero the expert-output accumulators (out_unet + out_vit, adjacent)
    hipMemsetAsync(out_unet, 0, 2 * 65536 * sizeof(float), stream);

    auto lin = [&](int ACT, const float* A, const float* Wt, const float* wsc,
                   const float* pos, const float* cond, const float* res, float osc,
                   const float* gate, int mPer, float* o, int M, int N, int K) {
        dim3 g(N / 32, (M + 31) / 32);
        if (ACT)
            linear_kernel<1><<<g, 256, 0, stream>>>(A, Wt, wsc, pos, cond, res, osc, gate, 4, mPer, o, M, N, K);
        else
            linear_kernel<0><<<g, 256, 0, stream>>>(A, Wt, wsc, pos, cond, res, osc, gate, 4, mPer, o, M, N, K);
    };

    // ---- time embedding
    femb_kernel<<<dim3(4), dim3(256), 0, stream>>>(time_vec, f_freq, f_phase, femb);
    lin(1, femb, w_f1, s_wf1, nullptr, nullptr, nullptr, 1.f, nullptr, 64, h1, 4, 1024, 256);
    lin(0, h1, w_f2, s_wf2, nullptr, nullptr, nullptr, 1.f, nullptr, 64, temb, 4, 512, 1024);

    // ---- path scales, pooled means, routers
    scale_kernel<<<dim3(1), dim3(64), 0, stream>>>(temb, w_scale, s_wsc, zeta, scale2);
    meanx_kernel<<<dim3(16), dim3(256), 0, stream>>>(x, mean_x);
    router_kernel<<<dim3(1), dim3(64), 0, stream>>>(mean_x, scale2, temb, w_ru, s_wru, w_rv, s_wrv,
                                                    zeta, rwu, rwv, out + 65536);
    make_inputs_kernel<<<dim3(256), dim3(256), 0, stream>>>(x, scale2, in_vit, in_unet);
    textp_kernel<<<dim3(12), dim3(256), 0, stream>>>(text_emb, textp);
    patchify_kernel<<<dim3(256), dim3(256), 0, stream>>>(in_vit, patchtok);

    // ---- UNet experts (skipped per-batch when router weight == 0)
    for (int e = 0; e < 4; ++e) {
        const float* gate = rwu + e;
        lin(0, temb, uw_time + (size_t)e * 98304, s_uwt + e * 192,
            nullptr, nullptr, nullptr, 1.f, nullptr, 64, tvec, 4, 192, 512);
        conv3x3_kernel<4, 8, 1, true, false><<<dim3(16, 24, 4), dim3(256), 0, stream>>>(
            in_unet, 4, uw_in + (size_t)e * 6912, s_uwin + e * 192, tvec, gate, 4, bufA, 192);
        conv3x3_kernel<8, 8, 1, false, false><<<dim3(16, 24, 4), dim3(256), 0, stream>>>(
            bufA, 192, uw_mid + (size_t)e * 331776, s_uwm + e * 192, nullptr, gate, 4, bufB, 192);
        conv3x3_kernel<8, 4, 0, false, true><<<dim3(16, 1, 4), dim3(256), 0, stream>>>(
            bufB, 192, uw_out + (size_t)e * 6912, s_uwo + e * 4, nullptr, gate, 4, out_unet, 4);
    }

    // ---- ViT experts
    for (int e = 0; e < 4; ++e) {
        const float* gate = rwv + e;
        lin(0, temb, vw_time + (size_t)e * 262144, s_vwti + e * 512,
            nullptr, nullptr, nullptr, 1.f, nullptr, 64, vcond, 4, 512, 512);
        lin(0, textp, vw_text + (size_t)e * 393216, s_vwte + e * 512,
            nullptr, nullptr, vcond, 1.f, nullptr, 64, vcond, 4, 512, 768);
        lin(0, patchtok, vw_patch + (size_t)e * 131072, s_vwp + e * 512,
            v_pos + (size_t)e * 32768, vcond, nullptr, 1.f, gate, 64, vtok, 256, 512, 256);
        lin(0, vtok, vw_qkv + (size_t)e * 786432, s_vwqkv + e * 1536,
            nullptr, nullptr, nullptr, 1.f, gate, 64, vqkv, 256, 1536, 512);
        vit_attn_kernel<<<dim3(32), dim3(64), 0, stream>>>(vqkv, gate, vao);
        lin(0, vao, vw_proj + (size_t)e * 262144, s_vwpr + e * 512,
            nullptr, nullptr, vtok, 0.70710678f, gate, 64, vtok2, 256, 512, 512);
        lin(1, vtok2, vw_mlp1 + (size_t)e * 1048576, s_vwm1 + e * 2048,
            nullptr, nullptr, nullptr, 1.f, gate, 64, vhid, 256, 2048, 512);
        lin(0, vhid, vw_mlp2 + (size_t)e * 1048576, s_vwm2 + e * 512,
            nullptr, nullptr, vtok2, 0.70710678f, gate, 64, vtok3, 256, 512, 2048);
        unpatch_kernel<<<dim3(256), dim3(256), 0, stream>>>(
            vtok3, vw_unp + (size_t)e * 131072, s_vwun + e * 256, gate, out_vit);
    }

    // ---- cross attention over flattened pixels
    ca_qkv_kernel<<<dim3(64), dim3(256), 0, stream>>>(out_unet, out_vit, ca_wq, s_cawq,
                                                      ca_wk, s_cawk, ca_wv, s_cawv, caq, cak, cav);
    ca_attn_kernel<<<dim3(256), dim3(64), 0, stream>>>(caq, cak, cav, cao);
    ca_blend_kernel<<<dim3(64), dim3(256), 0, stream>>>(cao, out_unet, ca_wo, s_cawo, aimg);

    // ---- gated combine -> d_out[0:65536]
    gate_kernel<<<dim3(64), dim3(256), 0, stream>>>(out_unet, aimg, gw1, s_gw1, gw2, s_gw2, out);
}

// Round 2
// 1080.220 us; speedup vs baseline: 3.0727x; 3.0727x over previous
//
#include <hip/hip_runtime.h>
#include <math.h>

// ---------------------------------------------------------------------------
// HDMOEM round 2: bf16 MFMA for mid conv + ViT GEMM stack, parallel cross-attn,
// merged launches. B=4, C=4, H=W=64, E=4 experts/path, TOPK=2.
// Router masks (d_in[3], d_in[4]) are all-True and ignored.
// Experts with router weight == 0.0 are skipped (exact: 0*x == 0).
// ---------------------------------------------------------------------------

#define DEV_INLINE __device__ __forceinline__

typedef __attribute__((ext_vector_type(8))) short bf16x8;
typedef __attribute__((ext_vector_type(4))) float f32x4;

DEV_INLINE float mp_silu_f(float x) { return x / ((1.f + __expf(-x)) * 0.596f); }

DEV_INLINE unsigned short f2bf(float x) {
    unsigned u = __float_as_uint(x);
    unsigned r = (u + 0x7fffu + ((u >> 16) & 1u)) >> 16;
    return (unsigned short)r;
}
DEV_INLINE float bf2f(unsigned short u) { return __uint_as_float(((unsigned)u) << 16); }

// ---------------------------------------------------------------------------
// merged rowscale: per-row 1/(sqrt(mean(w^2)+1e-8)*sqrt(fan))
struct RsEnt { const float* w; float* o; int fan; int rowStart; };
struct RsTab { RsEnt e[23]; };

__global__ void rowscale_all_kernel(RsTab t) {
    int r = blockIdx.x;
    int ti = 0;
#pragma unroll
    for (int j = 1; j < 23; ++j)
        if (r >= t.e[j].rowStart) ti = j;
    const float* p = t.e[ti].w;
    int fan = t.e[ti].fan;
    int row = r - t.e[ti].rowStart;
    p += (size_t)row * fan;
    float s = 0.f;
    for (int i = threadIdx.x; i < fan; i += 256) { float v = p[i]; s += v * v; }
    __shared__ float red[256];
    red[threadIdx.x] = s;
    __syncthreads();
    for (int st = 128; st > 0; st >>= 1) {
        if (threadIdx.x < st) red[threadIdx.x] += red[threadIdx.x + st];
        __syncthreads();
    }
    if (threadIdx.x == 0) {
        float mean = red[0] / (float)fan;
        t.e[ti].o[row] = 1.f / sqrtf((mean + 1e-8f) * (float)fan);
    }
}

// ---- transpose+convert mid-conv weights: [e][oc][ic][3][3] f32 -> [e][tap][oc][ic] bf16
__global__ void wmid_cvt_kernel(const float* __restrict__ w, unsigned short* __restrict__ wt) {
    int i = blockIdx.x * 256 + threadIdx.x;
    if (i >= 4 * 9 * 192 * 192) return;
    int ic = i % 192;
    int t = i / 192;
    int oc = t % 192; t /= 192;
    int tap = t % 9;
    int e = t / 9;
    wt[i] = f2bf(w[(((size_t)(e * 192 + oc) * 192 + ic) * 9) + tap]);
}

// ---- Fourier time embedding
__global__ void femb_kernel(const float* __restrict__ tv, const float* __restrict__ fr,
                            const float* __restrict__ ph, float* __restrict__ femb) {
    int i = blockIdx.x * 256 + threadIdx.x;
    if (i >= 1024) return;
    int b = i >> 8, j = i & 255;
    femb[i] = 1.41421356237f * cosf(6.28318530717958647f * (tv[b] * fr[j] + ph[j]));
}

// ---- f32 tiled linear (small-M GEMMs: time embeddings / cond vectors)
template <int ACT>
__global__ void linear_kernel(const float* __restrict__ A, const float* __restrict__ W,
                              const float* __restrict__ wsc,
                              const float* __restrict__ res, float outscale,
                              float* __restrict__ out, int M, int N, int K) {
    int bm = blockIdx.y * 32, bn = blockIdx.x * 32;
    __shared__ float As[32][33], Bs[32][33];
    int tid = threadIdx.x;
    int ty = tid >> 4, tx = tid & 15;
    float acc00 = 0.f, acc01 = 0.f, acc10 = 0.f, acc11 = 0.f;
    for (int k0 = 0; k0 < K; k0 += 32) {
#pragma unroll
        for (int i = 0; i < 4; ++i) {
            int idx = tid + i * 256;
            int r = idx >> 5, c = idx & 31;
            int m = bm + r;
            As[r][c] = (m < M) ? A[(size_t)m * K + k0 + c] : 0.f;
            Bs[r][c] = W[(size_t)(bn + r) * K + k0 + c];
        }
        __syncthreads();
#pragma unroll
        for (int kk = 0; kk < 32; ++kk) {
            float a0 = As[ty][kk], a1 = As[ty + 16][kk];
            float b0 = Bs[tx][kk], b1 = Bs[tx + 16][kk];
            acc00 += a0 * b0; acc01 += a0 * b1;
            acc10 += a1 * b0; acc11 += a1 * b1;
        }
        __syncthreads();
    }
    float accs[2][2] = {{acc00, acc01}, {acc10, acc11}};
#pragma unroll
    for (int im = 0; im < 2; ++im) {
        int m = bm + ty + im * 16;
        if (m >= M) continue;
#pragma unroll
        for (int jn = 0; jn < 2; ++jn) {
            int n = bn + tx + jn * 16;
            float val = accs[im][jn] * wsc[n];
            if (ACT == 1) val = mp_silu_f(val);
            if (res) val = (val + res[(size_t)m * N + n]) * outscale;
            out[(size_t)m * N + n] = val;
        }
    }
}

// ---- scale router
__global__ void scale_kernel(const float* __restrict__ temb, const float* __restrict__ w,
                             const float* __restrict__ wsc, const float* __restrict__ zeta,
                             float* __restrict__ scale2) {
    __shared__ float lg[8];
    int t = threadIdx.x;
    if (t < 8) {
        int b = t >> 1, o = t & 1;
        float s = 0.f;
        for (int k = 0; k < 512; ++k) s += temb[b * 512 + k] * w[o * 512 + k];
        lg[t] = s * wsc[o] / zeta[0];
    }
    __syncthreads();
    if (t < 4) {
        float a = lg[t * 2], b2 = lg[t * 2 + 1];
        float m = fmaxf(a, b2);
        float e0 = expf(a - m), e1 = expf(b2 - m);
        float inv = 2.f / (e0 + e1);
        scale2[t * 2] = e0 * inv;
        scale2[t * 2 + 1] = e1 * inv;
    }
}

__global__ void meanx_kernel(const float* __restrict__ x, float* __restrict__ mean_x) {
    int bc = blockIdx.x;
    float s = 0.f;
    for (int i = threadIdx.x; i < 4096; i += 256) s += x[bc * 4096 + i];
    __shared__ float red[256];
    red[threadIdx.x] = s;
    __syncthreads();
    for (int st = 128; st > 0; st >>= 1) {
        if (threadIdx.x < st) red[threadIdx.x] += red[threadIdx.x + st];
        __syncthreads();
    }
    if (threadIdx.x == 0) mean_x[bc] = red[0] * (1.f / 4096.f);
}

__global__ void router_kernel(const float* __restrict__ mean_x, const float* __restrict__ scale2,
                              const float* __restrict__ temb,
                              const float* __restrict__ wu, const float* __restrict__ su,
                              const float* __restrict__ wv, const float* __restrict__ sv,
                              const float* __restrict__ zeta,
                              float* __restrict__ rwu, float* __restrict__ rwv,
                              float* __restrict__ probs_out) {
    __shared__ float lg[2][4][4];
    int t = threadIdx.x;
    if (t < 32) {
        int r = t >> 4, b = (t >> 2) & 3, e = t & 3;
        const float* w = (r == 0) ? wu : wv;
        const float* sc = (r == 0) ? su : sv;
        float ps = scale2[b * 2 + (r == 0 ? 1 : 0)];
        float acc = 0.f;
        for (int c = 0; c < 4; ++c) acc += mean_x[b * 4 + c] * ps * w[e * 516 + c];
        for (int j = 0; j < 512; ++j) acc += temb[b * 512 + j] * w[e * 516 + 4 + j];
        lg[r][b][e] = acc * sc[e] / zeta[0];
    }
    __syncthreads();
    if (t < 8) {
        int r = t >> 2, b = t & 3;
        float p[4];
        float mx = -1e30f;
        for (int e = 0; e < 4; ++e) mx = fmaxf(mx, lg[r][b][e]);
        float sum = 0.f;
        for (int e = 0; e < 4; ++e) { p[e] = expf(lg[r][b][e] - mx); sum += p[e]; }
        for (int e = 0; e < 4; ++e) p[e] /= sum;
        int i1 = 0;
        for (int e = 1; e < 4; ++e) if (p[e] > p[i1]) i1 = e;
        int i2 = -1;
        for (int e = 0; e < 4; ++e) { if (e == i1) continue; if (i2 < 0 || p[e] > p[i2]) i2 = e; }
        float inv = 1.f / (p[i1] + p[i2]);
        float* rw = (r == 0) ? rwu : rwv;
        for (int e = 0; e < 4; ++e) rw[b * 4 + e] = 0.f;
        rw[b * 4 + i1] = p[i1] * inv;
        rw[b * 4 + i2] = p[i2] * inv;
        for (int e = 0; e < 4; ++e) probs_out[r * 16 + b * 4 + e] = p[e];
    }
}

__global__ void make_inputs_kernel(const float* __restrict__ x, const float* __restrict__ scale2,
                                   float* __restrict__ in_vit, float* __restrict__ in_unet) {
    int i = blockIdx.x * 256 + threadIdx.x;
    if (i >= 65536) return;
    int b = i >> 14;
    float v = x[i];
    in_vit[i] = scale2[b * 2] * v;
    in_unet[i] = scale2[b * 2 + 1] * v;
}

__global__ void textp_kernel(const float* __restrict__ te, float* __restrict__ tp) {
    int i = blockIdx.x * 256 + threadIdx.x;
    if (i >= 3072) return;
    int b = i / 768, f = i % 768;
    float s = 0.f;
    for (int t = 0; t < 77; ++t) s += te[(size_t)(b * 77 + t) * 768 + f];
    tp[i] = s * (1.f / 77.f);
}

__global__ void patchify_kernel(const float* __restrict__ in_vit, float* __restrict__ pt) {
    int i = blockIdx.x * 256 + threadIdx.x;
    if (i >= 65536) return;
    int b = i >> 14;
    int r = i & 16383;
    int s = r >> 8, f = r & 255;
    int c = f >> 6, py = (f >> 3) & 7, px = f & 7;
    int gy = s >> 3, gx = s & 7;
    pt[i] = in_vit[((b * 4 + c) * 64 + gy * 8 + py) * 64 + gx * 8 + px];
}

// ---------------------------------------------------------------------------
// conv_in: NCHW f32 [B,4,64,64] -> NHWC bf16 [B,64,64,192], (1+tmod)*silu epilogue
__global__ void conv_in_kernel(const float* __restrict__ in, const float* __restrict__ w,
                               const float* __restrict__ wsc, const float* __restrict__ tmod,
                               const float* __restrict__ gate,
                               unsigned short* __restrict__ out) {
    int b = blockIdx.z;
    if (gate[b * 4] == 0.f) return;
    int tileIdx = blockIdx.x;
    int ty0 = (tileIdx >> 2) * 16, tx0 = (tileIdx & 3) * 16;
    int oc0 = blockIdx.y * 8;
    int lty = threadIdx.x >> 4, ltx = threadIdx.x & 15;
    int y = ty0 + lty, x = tx0 + ltx;
    __shared__ float tile[4][18][18];
    for (int i = threadIdx.x; i < 4 * 18 * 18; i += 256) {
        int ic = i / 324, rr = (i / 18) % 18, cc = i % 18;
        int gy = ty0 - 1 + rr, gx = tx0 - 1 + cc;
        float v = 0.f;
        if (gy >= 0 && gy < 64 && gx >= 0 && gx < 64)
            v = in[((b * 4 + ic) * 64 + gy) * 64 + gx];
        tile[ic][rr][cc] = v;
    }
    __syncthreads();
    float win[4][9];
#pragma unroll
    for (int ic = 0; ic < 4; ++ic)
#pragma unroll
        for (int ky = 0; ky < 3; ++ky)
#pragma unroll
            for (int kx = 0; kx < 3; ++kx)
                win[ic][ky * 3 + kx] = tile[ic][lty + ky][ltx + kx];
#pragma unroll
    for (int o = 0; o < 8; ++o) {
        int oc = oc0 + o;
        float acc = 0.f;
#pragma unroll
        for (int ic = 0; ic < 4; ++ic) {
            const float* wp = w + (size_t)(oc * 4 + ic) * 9;
#pragma unroll
            for (int kk = 0; kk < 9; ++kk) acc += wp[kk] * win[ic][kk];
        }
        float val = acc * wsc[oc] * (1.f + tmod[b * 768 + oc]);
        val = mp_silu_f(val);
        out[((b * 64 + y) * 64 + x) * 192 + oc] = f2bf(val);
    }
}

// ---------------------------------------------------------------------------
// mid conv: implicit-GEMM bf16 MFMA. in/out NHWC bf16 [4,64,64,192].
// wt: [9][192 oc][192 ic] bf16 (expert slice). Grid (32 Mtiles, 3 Ntiles, 4 b).
__global__ __launch_bounds__(256) void conv_mid_mfma(
    const unsigned short* __restrict__ in, const unsigned short* __restrict__ wt,
    const float* __restrict__ wsc, const float* __restrict__ gate,
    unsigned short* __restrict__ out) {
    int b = blockIdx.z;
    if (gate[b * 4] == 0.f) return;
    int y0 = blockIdx.x * 2;
    int oc0 = blockIdx.y * 64;
    int wid = threadIdx.x >> 6, lane = threadIdx.x & 63;
    int wm = wid >> 1, wn = wid & 1;
    int l15 = lane & 15, lq = lane >> 4;

    __shared__ unsigned short Alds[4 * 66 * 40];  // rows y0-1..y0+2, x -1..64, 32 ic (pad 40)
    f32x4 acc[4][2];
#pragma unroll
    for (int g = 0; g < 4; ++g)
#pragma unroll
        for (int f = 0; f < 2; ++f) acc[g][f] = (f32x4){0.f, 0.f, 0.f, 0.f};

    for (int icc = 0; icc < 6; ++icc) {
        int ic0 = icc * 32;
        for (int i = threadIdx.x; i < 1056; i += 256) {
            int q = i & 3;
            int xx = (i >> 2) % 66;
            int r = (i >> 2) / 66;
            int y = y0 - 1 + r, xg = xx - 1;
            uint4 val = {0u, 0u, 0u, 0u};
            if (y >= 0 && y < 64 && xg >= 0 && xg < 64)
                val = *(const uint4*)&in[((b * 64 + y) * 64 + xg) * 192 + ic0 + q * 8];
            *(uint4*)&Alds[(r * 66 + xx) * 40 + q * 8] = val;
        }
        __syncthreads();
#pragma unroll
        for (int tap = 0; tap < 9; ++tap) {
            int ky = tap / 3, kx = tap % 3;
            bf16x8 bfr[2];
#pragma unroll
            for (int fn = 0; fn < 2; ++fn) {
                int oc = oc0 + wn * 32 + fn * 16 + l15;
                bfr[fn] = *(const bf16x8*)&wt[(size_t)(tap * 192 + oc) * 192 + ic0 + 8 * lq];
            }
            int r = wm + ky;
#pragma unroll
            for (int g = 0; g < 4; ++g) {
                int xx = g * 16 + l15 + kx;
                bf16x8 afr = *(const bf16x8*)&Alds[(r * 66 + xx) * 40 + 8 * lq];
                acc[g][0] = __builtin_amdgcn_mfma_f32_16x16x32_bf16(afr, bfr[0], acc[g][0], 0, 0, 0);
                acc[g][1] = __builtin_amdgcn_mfma_f32_16x16x32_bf16(afr, bfr[1], acc[g][1], 0, 0, 0);
            }
        }
        __syncthreads();
    }
    int orow = y0 + wm;
#pragma unroll
    for (int g = 0; g < 4; ++g)
#pragma unroll
        for (int fn = 0; fn < 2; ++fn) {
            int oc = oc0 + wn * 32 + fn * 16 + l15;
            float ws = wsc[oc];
#pragma unroll
            for (int r2 = 0; r2 < 4; ++r2) {
                int px = g * 16 + lq * 4 + r2;
                float v = acc[g][fn][r2] * ws;
                v = mp_silu_f(v);
                out[((b * 64 + orow) * 64 + px) * 192 + oc] = f2bf(v);
            }
        }
}

// ---------------------------------------------------------------------------
// conv_out: NHWC bf16 -> accumulate gated f32 NCHW into out_unet. OC=4.
__global__ void conv_out_kernel(const unsigned short* __restrict__ in,
                                const float* __restrict__ w, const float* __restrict__ wsc,
                                const float* __restrict__ gate, float* __restrict__ out) {
    int b = blockIdx.z;
    float g = gate[b * 4];
    if (g == 0.f) return;
    int tileIdx = blockIdx.x;
    int ty0 = (tileIdx >> 2) * 16, tx0 = (tileIdx & 3) * 16;
    int lty = threadIdx.x >> 4, ltx = threadIdx.x & 15;
    int y = ty0 + lty, x = tx0 + ltx;
    __shared__ float tile[8][18][18];
    float acc[4] = {0.f, 0.f, 0.f, 0.f};
    for (int c0 = 0; c0 < 192; c0 += 8) {
        for (int i = threadIdx.x; i < 324; i += 256) {
            int rr = i / 18, cc = i % 18;
            int gy = ty0 - 1 + rr, gx = tx0 - 1 + cc;
            if (gy >= 0 && gy < 64 && gx >= 0 && gx < 64) {
                uint4 raw = *(const uint4*)&in[((b * 64 + gy) * 64 + gx) * 192 + c0];
                tile[0][rr][cc] = bf2f((unsigned short)(raw.x & 0xffff));
                tile[1][rr][cc] = bf2f((unsigned short)(raw.x >> 16));
                tile[2][rr][cc] = bf2f((unsigned short)(raw.y & 0xffff));
                tile[3][rr][cc] = bf2f((unsigned short)(raw.y >> 16));
                tile[4][rr][cc] = bf2f((unsigned short)(raw.z & 0xffff));
                tile[5][rr][cc] = bf2f((unsigned short)(raw.z >> 16));
                tile[6][rr][cc] = bf2f((unsigned short)(raw.w & 0xffff));
                tile[7][rr][cc] = bf2f((unsigned short)(raw.w >> 16));
            } else {
#pragma unroll
                for (int ic = 0; ic < 8; ++ic) tile[ic][rr][cc] = 0.f;
            }
        }
        __syncthreads();
#pragma unroll
        for (int ic = 0; ic < 8; ++ic) {
            float win[9];
#pragma unroll
            for (int ky = 0; ky < 3; ++ky)
#pragma unroll
                for (int kx = 0; kx < 3; ++kx)
                    win[ky * 3 + kx] = tile[ic][lty + ky][ltx + kx];
#pragma unroll
            for (int o = 0; o < 4; ++o) {
                const float* wp = w + (size_t)(o * 192 + c0 + ic) * 9;
#pragma unroll
                for (int kk = 0; kk < 9; ++kk) acc[o] += wp[kk] * win[kk];
            }
        }
        __syncthreads();
    }
#pragma unroll
    for (int o = 0; o < 4; ++o)
        out[((b * 4 + o) * 64 + y) * 64 + x] += g * acc[o] * wsc[o];
}

// ---------------------------------------------------------------------------
// bf16 MFMA linear, expert-merged via gridDim.z. A f32 [M,K] staged->bf16 LDS;
// W f32 [N,K] converted on the fly. Epilogue: wsc, +pos, *(1+cond), ACT, (v+res)*osc.
template <int ACT>
__global__ __launch_bounds__(256) void mfma_linear_kernel(
    const float* __restrict__ A, int aE,
    const float* __restrict__ W, int wE,
    const float* __restrict__ wsc, int wscE,
    const float* __restrict__ pos, int posE,
    const float* __restrict__ cond, int condRow, int condE,
    const float* __restrict__ res, int resE, float outscale,
    const float* __restrict__ gate,
    float* __restrict__ out, int outE,
    int M, int N, int K) {
    int e = blockIdx.z;
    int bm = blockIdx.y * 32, bn = blockIdx.x * 64;
    if (gate && gate[(bm >> 6) * 4 + e] == 0.f) return;
    A += (size_t)e * aE;
    W += (size_t)e * wE;
    wsc += (size_t)e * wscE;
    if (pos) pos += (size_t)e * posE;
    if (cond) cond += (size_t)e * condE;
    if (res) res += (size_t)e * resE;
    out += (size_t)e * outE;

    int wid = threadIdx.x >> 6, lane = threadIdx.x & 63;
    int wm = wid >> 1, wn = wid & 1;
    int l15 = lane & 15, lq = lane >> 4;
    __shared__ unsigned short Alds[32 * 72];
    f32x4 acc[2];
    acc[0] = (f32x4){0.f, 0.f, 0.f, 0.f};
    acc[1] = (f32x4){0.f, 0.f, 0.f, 0.f};

    for (int k0 = 0; k0 < K; k0 += 64) {
#pragma unroll
        for (int p = 0; p < 2; ++p) {
            int i = threadIdx.x + p * 256;
            int row = i >> 4, kq = (i & 15) * 4;
            float4 va = *(const float4*)&A[(size_t)(bm + row) * K + k0 + kq];
            ushort4 sv;
            sv.x = f2bf(va.x); sv.y = f2bf(va.y); sv.z = f2bf(va.z); sv.w = f2bf(va.w);
            *(ushort4*)&Alds[row * 72 + kq] = sv;
        }
        __syncthreads();
#pragma unroll
        for (int ks = 0; ks < 2; ++ks) {
            bf16x8 afr = *(const bf16x8*)&Alds[(wm * 16 + l15) * 72 + ks * 32 + 8 * lq];
#pragma unroll
            for (int fn = 0; fn < 2; ++fn) {
                int n = bn + wn * 32 + fn * 16 + l15;
                const float* wp = &W[(size_t)n * K + k0 + ks * 32 + 8 * lq];
                float4 w0 = *(const float4*)wp;
                float4 w1 = *(const float4*)(wp + 4);
                bf16x8 bfr;
                bfr[0] = (short)f2bf(w0.x); bfr[1] = (short)f2bf(w0.y);
                bfr[2] = (short)f2bf(w0.z); bfr[3] = (short)f2bf(w0.w);
                bfr[4] = (short)f2bf(w1.x); bfr[5] = (short)f2bf(w1.y);
                bfr[6] = (short)f2bf(w1.z); bfr[7] = (short)f2bf(w1.w);
                acc[fn] = __builtin_amdgcn_mfma_f32_16x16x32_bf16(afr, bfr, acc[fn], 0, 0, 0);
            }
        }
        __syncthreads();
    }
#pragma unroll
    for (int fn = 0; fn < 2; ++fn) {
        int n = bn + wn * 32 + fn * 16 + l15;
        float ws = wsc[n];
#pragma unroll
        for (int r = 0; r < 4; ++r) {
            int m = bm + wm * 16 + lq * 4 + r;
            float val = acc[fn][r] * ws;
            if (pos) val += pos[(m & 63) * N + n];
            if (cond) val *= (1.f + cond[(m >> 6) * condRow + n]);
            if (ACT) val = mp_silu_f(val);
            if (res) val = (val + res[(size_t)m * N + n]) * outscale;
            out[(size_t)m * N + n] = val;
        }
    }
}

// ---- ViT self-attention, merged over (e,b,h); grid 128 x 64 threads
__global__ void vit_attn_kernel(const float* __restrict__ qkv_base,
                                const float* __restrict__ rwv,
                                float* __restrict__ out_base) {
    int e = blockIdx.x >> 5, b = (blockIdx.x >> 3) & 3, h = blockIdx.x & 7;
    if (rwv[b * 4 + e] == 0.f) return;
    const float* qkv = qkv_base + (size_t)e * 393216;
    float* out = out_base + (size_t)e * 131072;
    __shared__ float ks[64][65], vs[64][65], sc[64][65];
    int tid = threadIdx.x;
    for (int i = tid; i < 4096; i += 64) {
        int j = i >> 6, d = i & 63;
        ks[j][d] = qkv[(size_t)(b * 64 + j) * 1536 + 512 + h * 64 + d];
        vs[j][d] = qkv[(size_t)(b * 64 + j) * 1536 + 1024 + h * 64 + d];
    }
    float qreg[64];
#pragma unroll
    for (int d = 0; d < 64; ++d) qreg[d] = qkv[(size_t)(b * 64 + tid) * 1536 + h * 64 + d];
    __syncthreads();
    float mx = -1e30f;
    for (int j = 0; j < 64; ++j) {
        float s = 0.f;
#pragma unroll
        for (int d = 0; d < 64; ++d) s += qreg[d] * ks[j][d];
        s *= 0.125f;
        sc[tid][j] = s;
        mx = fmaxf(mx, s);
    }
    float sum = 0.f;
    for (int j = 0; j < 64; ++j) { float ee = __expf(sc[tid][j] - mx); sc[tid][j] = ee; sum += ee; }
    float inv = 1.f / sum;
    float accd[64];
#pragma unroll
    for (int d = 0; d < 64; ++d) accd[d] = 0.f;
    for (int j = 0; j < 64; ++j) {
        float ee = sc[tid][j];
#pragma unroll
        for (int d = 0; d < 64; ++d) accd[d] += ee * vs[j][d];
    }
#pragma unroll
    for (int d = 0; d < 64; ++d) out[(size_t)(b * 64 + tid) * 512 + h * 64 + d] = accd[d] * inv;
}

// ---- unpatchify + gated sum over experts: vout [4e][B,64,256] -> out_vit NCHW
__global__ void unpatch_scatter_kernel(const float* __restrict__ vout,
                                       const float* __restrict__ rwv,
                                       float* __restrict__ out_vit) {
    int i = blockIdx.x * 256 + threadIdx.x;
    if (i >= 65536) return;
    int b = i >> 14;
    int c = (i >> 12) & 3, y = (i >> 6) & 63, x = i & 63;
    int f = c * 64 + (y & 7) * 8 + (x & 7);
    int s = (y >> 3) * 8 + (x >> 3);
    int idx = (b * 64 + s) * 256 + f;
    float acc = 0.f;
#pragma unroll
    for (int e = 0; e < 4; ++e) {
        float g = rwv[b * 4 + e];
        if (g != 0.f) acc += g * vout[e * 65536 + idx];
    }
    out_vit[i] = acc;
}

// ---- cross-attn q/k/v prep
__global__ void ca_qkv_kernel(const float* __restrict__ ou, const float* __restrict__ ov,
                              const float* __restrict__ wq, const float* __restrict__ sq,
                              const float* __restrict__ wk, const float* __restrict__ sk,
                              const float* __restrict__ wv, const float* __restrict__ sv,
                              float* __restrict__ q, float* __restrict__ kx, float* __restrict__ vx) {
    int i = blockIdx.x * 256 + threadIdx.x;
    if (i >= 16384) return;
    int b = i >> 12, t = i & 4095;
    float u[4], c[4];
#pragma unroll
    for (int cc = 0; cc < 4; ++cc) {
        u[cc] = ou[(size_t)(b * 4 + cc) * 4096 + t];
        c[cc] = ov[(size_t)(b * 4 + cc) * 4096 + t];
    }
#pragma unroll
    for (int o = 0; o < 4; ++o) {
        float aq = 0.f, ak = 0.f, av = 0.f;
#pragma unroll
        for (int cc = 0; cc < 4; ++cc) {
            aq += wq[o * 4 + cc] * u[cc];
            ak += wk[o * 4 + cc] * c[cc];
            av += wv[o * 4 + cc] * c[cc];
        }
        q[(size_t)(b * 4096 + t) * 4 + o] = aq * sq[o];
        kx[(size_t)(b * 4096 + t) * 4 + o] = ak * sk[o];
        vx[(size_t)(b * 4096 + t) * 4 + o] = av * sv[o];
    }
}

// ---- cross-attn: 4 key-segments per block, LDS online-softmax merge
__global__ void ca_attn_kernel(const float* __restrict__ q, const float* __restrict__ k,
                               const float* __restrict__ v, float* __restrict__ o) {
    int b = blockIdx.x >> 6;
    int lq = threadIdx.x & 63, seg = threadIdx.x >> 6;
    int qt = ((blockIdx.x & 63) << 6) + lq;
    float4 qv = *(const float4*)&q[(size_t)(b * 4096 + qt) * 4];
    const float4* kb = (const float4*)(k + (size_t)b * 16384);
    const float4* vb = (const float4*)(v + (size_t)b * 16384);
    float m = -1e30f, l = 0.f, a0 = 0.f, a1 = 0.f, a2 = 0.f, a3 = 0.f;
    int j0 = seg * 1024;
    for (int j = j0; j < j0 + 1024; ++j) {
        float4 kk = kb[j];
        float s = 0.5f * (qv.x * kk.x + qv.y * kk.y + qv.z * kk.z + qv.w * kk.w);
        float nm = fmaxf(m, s);
        float corr = __expf(m - nm);
        float ee = __expf(s - nm);
        float4 vv = vb[j];
        l = l * corr + ee;
        a0 = a0 * corr + ee * vv.x;
        a1 = a1 * corr + ee * vv.y;
        a2 = a2 * corr + ee * vv.z;
        a3 = a3 * corr + ee * vv.w;
        m = nm;
    }
    __shared__ float red[4][64][8];
    red[seg][lq][0] = m; red[seg][lq][1] = l;
    red[seg][lq][2] = a0; red[seg][lq][3] = a1;
    red[seg][lq][4] = a2; red[seg][lq][5] = a3;
    __syncthreads();
    if (seg == 0) {
#pragma unroll
        for (int s2 = 1; s2 < 4; ++s2) {
            float m2 = red[s2][lq][0], l2 = red[s2][lq][1];
            float nm = fmaxf(m, m2);
            float c1 = __expf(m - nm), c2 = __expf(m2 - nm);
            l = l * c1 + l2 * c2;
            a0 = a0 * c1 + red[s2][lq][2] * c2;
            a1 = a1 * c1 + red[s2][lq][3] * c2;
            a2 = a2 * c1 + red[s2][lq][4] * c2;
            a3 = a3 * c1 + red[s2][lq][5] * c2;
            m = nm;
        }
        float inv = 1.f / l;
        float* op = &o[(size_t)(b * 4096 + qt) * 4];
        op[0] = a0 * inv; op[1] = a1 * inv; op[2] = a2 * inv; op[3] = a3 * inv;
    }
}

__global__ void ca_blend_kernel(const float* __restrict__ ao, const float* __restrict__ ou,
                                const float* __restrict__ wo, const float* __restrict__ so,
                                float* __restrict__ img) {
    int i = blockIdx.x * 256 + threadIdx.x;
    if (i >= 16384) return;
    int b = i >> 12, t = i & 4095;
    float oo[4];
#pragma unroll
    for (int j = 0; j < 4; ++j) oo[j] = ao[(size_t)(b * 4096 + t) * 4 + j];
    const float inv = 1.21267812518f;  // 1/sqrt(0.2^2+0.8^2)
#pragma unroll
    for (int c = 0; c < 4; ++c) {
        float s = 0.f;
#pragma unroll
        for (int j = 0; j < 4; ++j) s += wo[c * 4 + j] * oo[j];
        s *= so[c];
        float qv = ou[(size_t)(b * 4 + c) * 4096 + t];
        img[(size_t)(b * 4 + c) * 4096 + t] = (0.2f * qv + 0.8f * s) * inv;
    }
}

__global__ void gate_kernel(const float* __restrict__ ou, const float* __restrict__ ai,
                            const float* __restrict__ gw1, const float* __restrict__ s1,
                            const float* __restrict__ gw2, const float* __restrict__ s2,
                            float* __restrict__ out) {
    int i = blockIdx.x * 256 + threadIdx.x;
    if (i >= 16384) return;
    int b = i >> 12, t = i & 4095;
    float u[4], a[4];
#pragma unroll
    for (int c = 0; c < 4; ++c) {
        u[c] = ou[(size_t)(b * 4 + c) * 4096 + t];
        a[c] = ai[(size_t)(b * 4 + c) * 4096 + t];
    }
    float mvec[4];
#pragma unroll
    for (int o = 0; o < 4; ++o) {
        float s = 0.f;
#pragma unroll
        for (int c = 0; c < 4; ++c) s += gw1[o * 8 + c] * u[c] + gw1[o * 8 + 4 + c] * a[c];
        mvec[o] = mp_silu_f(s * s1[o]);
    }
    float g0 = 0.f, g1 = 0.f;
#pragma unroll
    for (int o = 0; o < 4; ++o) { g0 += gw2[o] * mvec[o]; g1 += gw2[4 + o] * mvec[o]; }
    g0 *= s2[0]; g1 *= s2[1];
    float mx = fmaxf(g0, g1);
    float e0 = expf(g0 - mx), e1 = expf(g1 - mx);
    float invd = 1.f / (e0 + e1);
    g0 = e0 * invd; g1 = e1 * invd;
#pragma unroll
    for (int c = 0; c < 4; ++c)
        out[(size_t)(b * 4 + c) * 4096 + t] = g0 * u[c] + g1 * a[c];
}

// ---------------------------------------------------------------------------
extern "C" void kernel_launch(void* const* d_in, const int* in_sizes, int n_in,
                              void* d_out, int out_size, void* d_ws, size_t ws_size,
                              hipStream_t stream) {
    (void)in_sizes; (void)n_in; (void)out_size; (void)ws_size;

    const float* x        = (const float*)d_in[0];
    const float* time_vec = (const float*)d_in[1];
    const float* text_emb = (const float*)d_in[2];
    const float* zeta     = (const float*)d_in[5];
    const float* f_freq   = (const float*)d_in[6];
    const float* f_phase  = (const float*)d_in[7];
    const float* w_f1     = (const float*)d_in[8];
    const float* w_f2     = (const float*)d_in[9];
    const float* w_scale  = (const float*)d_in[10];
    const float* w_ru     = (const float*)d_in[11];
    const float* w_rv     = (const float*)d_in[12];
    const float* uw_in    = (const float*)d_in[13];
    const float* uw_time  = (const float*)d_in[14];
    const float* uw_mid   = (const float*)d_in[15];
    const float* uw_out   = (const float*)d_in[16];
    const float* vw_patch = (const float*)d_in[17];
    const float* v_pos    = (const float*)d_in[18];
    const float* vw_qkv   = (const float*)d_in[19];
    const float* vw_proj  = (const float*)d_in[20];
    const float* vw_time  = (const float*)d_in[21];
    const float* vw_text  = (const float*)d_in[22];
    const float* vw_mlp1  = (const float*)d_in[23];
    const float* vw_mlp2  = (const float*)d_in[24];
    const float* vw_unp   = (const float*)d_in[25];
    const float* ca_wq    = (const float*)d_in[26];
    const float* ca_wk    = (const float*)d_in[27];
    const float* ca_wv    = (const float*)d_in[28];
    const float* ca_wo    = (const float*)d_in[29];
    const float* gw1      = (const float*)d_in[30];
    const float* gw2      = (const float*)d_in[31];

    float* out = (float*)d_out;

    float* Wp = (float*)d_ws;
    size_t off = 0;
    auto alloc = [&](size_t n) { float* p = Wp + off; off += (n + 3) & ~(size_t)3; return p; };

    float* s_wf1   = alloc(1024);
    float* s_wf2   = alloc(512);
    float* s_wsc   = alloc(2);
    float* s_wru   = alloc(4);
    float* s_wrv   = alloc(4);
    float* s_uwin  = alloc(768);
    float* s_uwt   = alloc(768);
    float* s_uwm   = alloc(768);
    float* s_uwo   = alloc(16);
    float* s_vwp   = alloc(2048);
    float* s_vwqkv = alloc(6144);
    float* s_vwpr  = alloc(2048);
    float* s_vwti  = alloc(2048);
    float* s_vwte  = alloc(2048);
    float* s_vwm1  = alloc(8192);
    float* s_vwm2  = alloc(2048);
    float* s_vwun  = alloc(1024);
    float* s_cawq  = alloc(4);
    float* s_cawk  = alloc(4);
    float* s_cawv  = alloc(4);
    float* s_cawo  = alloc(4);
    float* s_gw1   = alloc(4);
    float* s_gw2   = alloc(2);

    float* femb    = alloc(1024);
    float* h1      = alloc(4096);
    float* temb    = alloc(2048);
    float* scale2  = alloc(8);
    float* mean_x  = alloc(16);
    float* rwu     = alloc(16);
    float* rwv     = alloc(16);
    float* textp   = alloc(3072);
    float* tvec    = alloc(3072);      // [4b][768] (4 experts x 192)
    float* patchtok= alloc(65536);
    float* in_unet = alloc(65536);
    float* in_vit  = alloc(65536);
    float* out_unet= alloc(65536);
    float* out_vit = alloc(65536);
    unsigned short* bufA  = (unsigned short*)alloc(1572864);  // NHWC bf16 [4,64,64,192]
    unsigned short* bufB  = (unsigned short*)alloc(1572864);
    unsigned short* wtmid = (unsigned short*)alloc(663552);   // [4e][9][192][192] bf16
    float* vcond   = alloc(8192);      // [4b][4e*512]
    float* vtok    = alloc(524288);    // [4e][256][512]
    float* vqkv    = alloc(1572864);   // [4e][256][1536]
    float* vao     = alloc(524288);
    float* vtok2   = alloc(524288);
    float* vhid    = alloc(2097152);   // [4e][256][2048]
    float* vtok3   = alloc(524288);
    float* vout    = alloc(262144);    // [4e][256][256]
    float* caq     = alloc(65536);
    float* cak     = alloc(65536);
    float* cav     = alloc(65536);
    float* cao     = alloc(65536);
    float* aimg    = alloc(65536);

    // ---- merged rowscale (23 tensors, one dispatch)
    RsTab tab;
    int rowCounts[23] = {1024, 512, 2, 4, 4, 768, 768, 768, 16, 2048, 6144, 2048,
                         2048, 2048, 8192, 2048, 1024, 4, 4, 4, 4, 4, 2};
    const float* srcs[23] = {w_f1, w_f2, w_scale, w_ru, w_rv, uw_in, uw_time, uw_mid, uw_out,
                             vw_patch, vw_qkv, vw_proj, vw_time, vw_text, vw_mlp1, vw_mlp2,
                             vw_unp, ca_wq, ca_wk, ca_wv, ca_wo, gw1, gw2};
    float* dsts[23] = {s_wf1, s_wf2, s_wsc, s_wru, s_wrv, s_uwin, s_uwt, s_uwm, s_uwo,
                       s_vwp, s_vwqkv, s_vwpr, s_vwti, s_vwte, s_vwm1, s_vwm2,
                       s_vwun, s_cawq, s_cawk, s_cawv, s_cawo, s_gw1, s_gw2};
    int fans[23] = {256, 1024, 512, 516, 516, 36, 512, 1728, 1728, 256, 512, 512,
                    512, 768, 512, 2048, 512, 4, 4, 4, 4, 8, 4};
    int cum = 0;
    for (int i = 0; i < 23; ++i) {
        tab.e[i].w = srcs[i]; tab.e[i].o = dsts[i];
        tab.e[i].fan = fans[i]; tab.e[i].rowStart = cum;
        cum += rowCounts[i];
    }
    rowscale_all_kernel<<<dim3(cum), dim3(256), 0, stream>>>(tab);

    // ---- mid-conv weight transpose+convert
    wmid_cvt_kernel<<<dim3((1327104 + 255) / 256), dim3(256), 0, stream>>>(uw_mid, wtmid);

    auto lin = [&](int ACT, const float* A, const float* Wt, const float* wsc,
                   const float* res, float osc, float* o, int M, int N, int K) {
        dim3 g(N / 32, (M + 31) / 32);
        if (ACT)
            linear_kernel<1><<<g, 256, 0, stream>>>(A, Wt, wsc, res, osc, o, M, N, K);
        else
            linear_kernel<0><<<g, 256, 0, stream>>>(A, Wt, wsc, res, osc, o, M, N, K);
    };

    // ---- time embedding chain
    femb_kernel<<<dim3(4), dim3(256), 0, stream>>>(time_vec, f_freq, f_phase, femb);
    lin(1, femb, w_f1, s_wf1, nullptr, 1.f, h1, 4, 1024, 256);
    lin(0, h1, w_f2, s_wf2, nullptr, 1.f, temb, 4, 512, 1024);

    scale_kernel<<<dim3(1), dim3(64), 0, stream>>>(temb, w_scale, s_wsc, zeta, scale2);
    meanx_kernel<<<dim3(16), dim3(256), 0, stream>>>(x, mean_x);
    router_kernel<<<dim3(1), dim3(64), 0, stream>>>(mean_x, scale2, temb, w_ru, s_wru, w_rv, s_wrv,
                                                    zeta, rwu, rwv, out + 65536);
    make_inputs_kernel<<<dim3(256), dim3(256), 0, stream>>>(x, scale2, in_vit, in_unet);
    textp_kernel<<<dim3(12), dim3(256), 0, stream>>>(text_emb, textp);
    patchify_kernel<<<dim3(256), dim3(256), 0, stream>>>(in_vit, patchtok);

    // merged per-expert time mod for UNet: tvec [4b][4e*192]
    lin(0, temb, uw_time, s_uwt, nullptr, 1.f, tvec, 4, 768, 512);

    hipMemsetAsync(out_unet, 0, 65536 * sizeof(float), stream);

    // ---- UNet experts (bufA/bufB reused per expert)
    for (int e = 0; e < 4; ++e) {
        const float* gate = rwu + e;
        conv_in_kernel<<<dim3(16, 24, 4), dim3(256), 0, stream>>>(
            in_unet, uw_in + (size_t)e * 6912, s_uwin + e * 192, tvec + e * 192, gate, bufA);
        conv_mid_mfma<<<dim3(32, 3, 4), dim3(256), 0, stream>>>(
            bufA, wtmid + (size_t)e * 331776, s_uwm + e * 192, gate, bufB);
        conv_out_kernel<<<dim3(16, 1, 4), dim3(256), 0, stream>>>(
            bufB, uw_out + (size_t)e * 6912, s_uwo + e * 4, gate, out_unet);
    }

    // ---- ViT cond vectors for all experts: vcond [4b][4e*512]
    lin(0, temb, vw_time, s_vwti, nullptr, 1.f, vcond, 4, 2048, 512);
    lin(0, textp, vw_text, s_vwte, vcond, 1.f, vcond, 4, 2048, 768);

    auto mlin = [&](int ACT, const float* A, int aE, const float* W2, int wE2,
                    const float* wsc, int wscE, const float* pos, int posE,
                    const float* cond, int condRow, int condE,
                    const float* res, int resE, float osc,
                    const float* gate, float* o, int outE, int M, int N, int K) {
        dim3 g(N / 64, M / 32, 4);
        if (ACT)
            mfma_linear_kernel<1><<<g, 256, 0, stream>>>(A, aE, W2, wE2, wsc, wscE, pos, posE,
                                                         cond, condRow, condE, res, resE, osc,
                                                         gate, o, outE, M, N, K);
        else
            mfma_linear_kernel<0><<<g, 256, 0, stream>>>(A, aE, W2, wE2, wsc, wscE, pos, posE,
                                                         cond, condRow, condE, res, resE, osc,
                                                         gate, o, outE, M, N, K);
    };

    // ---- ViT expert stack (all experts per dispatch via grid.z)
    mlin(0, patchtok, 0, vw_patch, 131072, s_vwp, 512, v_pos, 32768,
         vcond, 2048, 512, nullptr, 0, 1.f, rwv, vtok, 131072, 256, 512, 256);
    mlin(0, vtok, 131072, vw_qkv, 786432, s_vwqkv, 1536, nullptr, 0,
         nullptr, 0, 0, nullptr, 0, 1.f, rwv, vqkv, 393216, 256, 1536, 512);
    vit_attn_kernel<<<dim3(128), dim3(64), 0, stream>>>(vqkv, rwv, vao);
    mlin(0, vao, 131072, vw_proj, 262144, s_vwpr, 512, nullptr, 0,
         nullptr, 0, 0, vtok, 131072, 0.70710678f, rwv, vtok2, 131072, 256, 512, 512);
    mlin(1, vtok2, 131072, vw_mlp1, 1048576, s_vwm1, 2048, nullptr, 0,
         nullptr, 0, 0, nullptr, 0, 1.f, rwv, vhid, 524288, 256, 2048, 512);
    mlin(0, vhid, 524288, vw_mlp2, 1048576, s_vwm2, 512, nullptr, 0,
         nullptr, 0, 0, vtok2, 131072, 0.70710678f, rwv, vtok3, 131072, 256, 512, 2048);
    mlin(0, vtok3, 131072, vw_unp, 131072, s_vwun, 256, nullptr, 0,
         nullptr, 0, 0, nullptr, 0, 1.f, rwv, vout, 65536, 256, 256, 512);
    unpatch_scatter_kernel<<<dim3(256), dim3(256), 0, stream>>>(vout, rwv, out_vit);

    // ---- cross attention
    ca_qkv_kernel<<<dim3(64), dim3(256), 0, stream>>>(out_unet, out_vit, ca_wq, s_cawq,
                                                      ca_wk, s_cawk, ca_wv, s_cawv, caq, cak, cav);
    ca_attn_kernel<<<dim3(256), dim3(256), 0, stream>>>(caq, cak, cav, cao);
    ca_blend_kernel<<<dim3(64), dim3(256), 0, stream>>>(cao, out_unet, ca_wo, s_cawo, aimg);

    // ---- gated combine -> d_out
    gate_kernel<<<dim3(64), dim3(256), 0, stream>>>(out_unet, aimg, gw1, s_gw1, gw2, s_gw2, out);
}

// Round 3
// 524.416 us; speedup vs baseline: 6.3292x; 2.0599x over previous
//
#include <hip/hip_runtime.h>
#include <math.h>

// ---------------------------------------------------------------------------
// HDMOEM round 3: slot-compacted UNet conv chain (top-2 experts, one dispatch
// per stage), split-K atomic conv_out, GEMV for M=4 linears, batched ca_attn.
// B=4, C=4, H=W=64, E=4 experts/path, TOPK=2. Router masks all-True, ignored.
// ---------------------------------------------------------------------------

#define DEV_INLINE __device__ __forceinline__

typedef __attribute__((ext_vector_type(8))) short bf16x8;
typedef __attribute__((ext_vector_type(4))) float f32x4;

DEV_INLINE float mp_silu_f(float x) { return x / ((1.f + __expf(-x)) * 0.596f); }

DEV_INLINE unsigned short f2bf(float x) {
    unsigned u = __float_as_uint(x);
    unsigned r = (u + 0x7fffu + ((u >> 16) & 1u)) >> 16;
    return (unsigned short)r;
}
DEV_INLINE float bf2f(unsigned short u) { return __uint_as_float(((unsigned)u) << 16); }

// ---------------------------------------------------------------------------
struct RsEnt { const float* w; float* o; int fan; int rowStart; };
struct RsTab { RsEnt e[23]; };

__global__ void rowscale_all_kernel(RsTab t) {
    int r = blockIdx.x;
    int ti = 0;
#pragma unroll
    for (int j = 1; j < 23; ++j)
        if (r >= t.e[j].rowStart) ti = j;
    const float* p = t.e[ti].w;
    int fan = t.e[ti].fan;
    int row = r - t.e[ti].rowStart;
    p += (size_t)row * fan;
    float s = 0.f;
    for (int i = threadIdx.x; i < fan; i += 256) { float v = p[i]; s += v * v; }
    __shared__ float red[256];
    red[threadIdx.x] = s;
    __syncthreads();
    for (int st = 128; st > 0; st >>= 1) {
        if (threadIdx.x < st) red[threadIdx.x] += red[threadIdx.x + st];
        __syncthreads();
    }
    if (threadIdx.x == 0) {
        float mean = red[0] / (float)fan;
        t.e[ti].o[row] = 1.f / sqrtf((mean + 1e-8f) * (float)fan);
    }
}

// ---- mid-conv weights: [e][oc][ic][3][3] f32 -> [e][tap][oc][ic] bf16
__global__ void wmid_cvt_kernel(const float* __restrict__ w, unsigned short* __restrict__ wt) {
    int i = blockIdx.x * 256 + threadIdx.x;
    if (i >= 4 * 9 * 192 * 192) return;
    int ic = i % 192;
    int t = i / 192;
    int oc = t % 192; t /= 192;
    int tap = t % 9;
    int e = t / 9;
    wt[i] = f2bf(w[(((size_t)(e * 192 + oc) * 192 + ic) * 9) + tap]);
}

__global__ void femb_kernel(const float* __restrict__ tv, const float* __restrict__ fr,
                            const float* __restrict__ ph, float* __restrict__ femb) {
    int i = blockIdx.x * 256 + threadIdx.x;
    if (i >= 1024) return;
    int b = i >> 8, j = i & 255;
    femb[i] = 1.41421356237f * cosf(6.28318530717958647f * (tv[b] * fr[j] + ph[j]));
}

// ---- wave-per-output GEMV for small-M linears: out[m,n]=epi(A[m,:]·W[n,:])
template <int ACT, int HASRES>
__global__ void gemv_kernel(const float* __restrict__ A, const float* __restrict__ W,
                            const float* __restrict__ wsc, const float* __restrict__ res,
                            float osc, float* __restrict__ out, int N, int K) {
    int o = blockIdx.x * 4 + (threadIdx.x >> 6);
    int lane = threadIdx.x & 63;
    int m = o / N, n = o % N;
    const float* a = A + (size_t)m * K;
    const float* w = W + (size_t)n * K;
    float s = 0.f;
    for (int k = lane; k < K; k += 64) s += a[k] * w[k];
#pragma unroll
    for (int sh = 32; sh > 0; sh >>= 1) s += __shfl_xor(s, sh);
    if (lane == 0) {
        float val = s * wsc[n];
        if (ACT) val = mp_silu_f(val);
        if (HASRES) val = (val + res[(size_t)m * N + n]) * osc;
        out[(size_t)m * N + n] = val;
    }
}

__global__ void scale_kernel(const float* __restrict__ temb, const float* __restrict__ w,
                             const float* __restrict__ wsc, const float* __restrict__ zeta,
                             float* __restrict__ scale2) {
    __shared__ float lg[8];
    int t = threadIdx.x;
    if (t < 8) {
        int b = t >> 1, o = t & 1;
        float s = 0.f;
        for (int k = 0; k < 512; ++k) s += temb[b * 512 + k] * w[o * 512 + k];
        lg[t] = s * wsc[o] / zeta[0];
    }
    __syncthreads();
    if (t < 4) {
        float a = lg[t * 2], b2 = lg[t * 2 + 1];
        float m = fmaxf(a, b2);
        float e0 = expf(a - m), e1 = expf(b2 - m);
        float inv = 2.f / (e0 + e1);
        scale2[t * 2] = e0 * inv;
        scale2[t * 2 + 1] = e1 * inv;
    }
}

__global__ void meanx_kernel(const float* __restrict__ x, float* __restrict__ mean_x) {
    int bc = blockIdx.x;
    float s = 0.f;
    for (int i = threadIdx.x; i < 4096; i += 256) s += x[bc * 4096 + i];
    __shared__ float red[256];
    red[threadIdx.x] = s;
    __syncthreads();
    for (int st = 128; st > 0; st >>= 1) {
        if (threadIdx.x < st) red[threadIdx.x] += red[threadIdx.x + st];
        __syncthreads();
    }
    if (threadIdx.x == 0) mean_x[bc] = red[0] * (1.f / 4096.f);
}

// ---- routers: probs + top2; unet side also emits slot tables (eidx, gain)
__global__ void router_kernel(const float* __restrict__ mean_x, const float* __restrict__ scale2,
                              const float* __restrict__ temb,
                              const float* __restrict__ wu, const float* __restrict__ su,
                              const float* __restrict__ wv, const float* __restrict__ sv,
                              const float* __restrict__ zeta,
                              int* __restrict__ eidx, float* __restrict__ gain,
                              float* __restrict__ rwv,
                              float* __restrict__ probs_out) {
    __shared__ float lg[2][4][4];
    int t = threadIdx.x;
    if (t < 32) {
        int r = t >> 4, b = (t >> 2) & 3, e = t & 3;
        const float* w = (r == 0) ? wu : wv;
        const float* sc = (r == 0) ? su : sv;
        float ps = scale2[b * 2 + (r == 0 ? 1 : 0)];
        float acc = 0.f;
        for (int c = 0; c < 4; ++c) acc += mean_x[b * 4 + c] * ps * w[e * 516 + c];
        for (int j = 0; j < 512; ++j) acc += temb[b * 512 + j] * w[e * 516 + 4 + j];
        lg[r][b][e] = acc * sc[e] / zeta[0];
    }
    __syncthreads();
    if (t < 8) {
        int r = t >> 2, b = t & 3;
        float p[4];
        float mx = -1e30f;
        for (int e = 0; e < 4; ++e) mx = fmaxf(mx, lg[r][b][e]);
        float sum = 0.f;
        for (int e = 0; e < 4; ++e) { p[e] = expf(lg[r][b][e] - mx); sum += p[e]; }
        for (int e = 0; e < 4; ++e) p[e] /= sum;
        int i1 = 0;
        for (int e = 1; e < 4; ++e) if (p[e] > p[i1]) i1 = e;
        int i2 = -1;
        for (int e = 0; e < 4; ++e) { if (e == i1) continue; if (i2 < 0 || p[e] > p[i2]) i2 = e; }
        float inv = 1.f / (p[i1] + p[i2]);
        if (r == 0) {
            eidx[b * 2] = i1; eidx[b * 2 + 1] = i2;
            gain[b * 2] = p[i1] * inv; gain[b * 2 + 1] = p[i2] * inv;
        } else {
            for (int e = 0; e < 4; ++e) rwv[b * 4 + e] = 0.f;
            rwv[b * 4 + i1] = p[i1] * inv;
            rwv[b * 4 + i2] = p[i2] * inv;
        }
        for (int e = 0; e < 4; ++e) probs_out[r * 16 + b * 4 + e] = p[e];
    }
}

__global__ void make_inputs_kernel(const float* __restrict__ x, const float* __restrict__ scale2,
                                   float* __restrict__ in_vit, float* __restrict__ in_unet) {
    int i = blockIdx.x * 256 + threadIdx.x;
    if (i >= 65536) return;
    int b = i >> 14;
    float v = x[i];
    in_vit[i] = scale2[b * 2] * v;
    in_unet[i] = scale2[b * 2 + 1] * v;
}

__global__ void textp_kernel(const float* __restrict__ te, float* __restrict__ tp) {
    int i = blockIdx.x * 256 + threadIdx.x;
    if (i >= 3072) return;
    int b = i / 768, f = i % 768;
    float s = 0.f;
    for (int t = 0; t < 77; ++t) s += te[(size_t)(b * 77 + t) * 768 + f];
    tp[i] = s * (1.f / 77.f);
}

__global__ void patchify_kernel(const float* __restrict__ in_vit, float* __restrict__ pt) {
    int i = blockIdx.x * 256 + threadIdx.x;
    if (i >= 65536) return;
    int b = i >> 14;
    int r = i & 16383;
    int s = r >> 8, f = r & 255;
    int c = f >> 6, py = (f >> 3) & 7, px = f & 7;
    int gy = s >> 3, gx = s & 7;
    pt[i] = in_vit[((b * 4 + c) * 64 + gy * 8 + py) * 64 + gx * 8 + px];
}

// ---------------------------------------------------------------------------
// conv_in (slots): NCHW f32 -> NHWC bf16 per slot. grid (16,24,8)
__global__ void conv_in_kernel(const float* __restrict__ in, const float* __restrict__ wbase,
                               const float* __restrict__ wscb, const float* __restrict__ tvec,
                               const int* __restrict__ eidx,
                               unsigned short* __restrict__ out) {
    int z = blockIdx.z, b = z >> 1;
    int e = eidx[z];
    const float* w = wbase + (size_t)e * 6912;
    const float* wsc = wscb + e * 192;
    const float* tmod = tvec + b * 768 + e * 192;
    int tileIdx = blockIdx.x;
    int ty0 = (tileIdx >> 2) * 16, tx0 = (tileIdx & 3) * 16;
    int oc0 = blockIdx.y * 8;
    int lty = threadIdx.x >> 4, ltx = threadIdx.x & 15;
    int y = ty0 + lty, x = tx0 + ltx;
    __shared__ float tile[4][18][18];
    for (int i = threadIdx.x; i < 4 * 18 * 18; i += 256) {
        int ic = i / 324, rr = (i / 18) % 18, cc = i % 18;
        int gy = ty0 - 1 + rr, gx = tx0 - 1 + cc;
        float v = 0.f;
        if (gy >= 0 && gy < 64 && gx >= 0 && gx < 64)
            v = in[((b * 4 + ic) * 64 + gy) * 64 + gx];
        tile[ic][rr][cc] = v;
    }
    __syncthreads();
    float win[4][9];
#pragma unroll
    for (int ic = 0; ic < 4; ++ic)
#pragma unroll
        for (int ky = 0; ky < 3; ++ky)
#pragma unroll
            for (int kx = 0; kx < 3; ++kx)
                win[ic][ky * 3 + kx] = tile[ic][lty + ky][ltx + kx];
#pragma unroll
    for (int o = 0; o < 8; ++o) {
        int oc = oc0 + o;
        float acc = 0.f;
#pragma unroll
        for (int ic = 0; ic < 4; ++ic) {
            const float* wp = w + (size_t)(oc * 4 + ic) * 9;
#pragma unroll
            for (int kk = 0; kk < 9; ++kk) acc += wp[kk] * win[ic][kk];
        }
        float val = acc * wsc[oc] * (1.f + tmod[oc]);
        val = mp_silu_f(val);
        out[((z * 64 + y) * 64 + x) * 192 + oc] = f2bf(val);
    }
}

// ---------------------------------------------------------------------------
// mid conv (slots): implicit-GEMM bf16 MFMA. grid (32,3,8)
__global__ __launch_bounds__(256) void conv_mid_mfma(
    const unsigned short* __restrict__ in, const unsigned short* __restrict__ wtbase,
    const float* __restrict__ wscb, const int* __restrict__ eidx,
    unsigned short* __restrict__ out) {
    int z = blockIdx.z;
    int e = eidx[z];
    const unsigned short* wt = wtbase + (size_t)e * 331776;
    const float* wsc = wscb + e * 192;
    int y0 = blockIdx.x * 2;
    int oc0 = blockIdx.y * 64;
    int wid = threadIdx.x >> 6, lane = threadIdx.x & 63;
    int wm = wid >> 1, wn = wid & 1;
    int l15 = lane & 15, lq = lane >> 4;

    __shared__ unsigned short Alds[4 * 66 * 40];
    f32x4 acc[4][2];
#pragma unroll
    for (int g = 0; g < 4; ++g)
#pragma unroll
        for (int f = 0; f < 2; ++f) acc[g][f] = (f32x4){0.f, 0.f, 0.f, 0.f};

    for (int icc = 0; icc < 6; ++icc) {
        int ic0 = icc * 32;
        for (int i = threadIdx.x; i < 1056; i += 256) {
            int q = i & 3;
            int xx = (i >> 2) % 66;
            int r = (i >> 2) / 66;
            int y = y0 - 1 + r, xg = xx - 1;
            uint4 val = {0u, 0u, 0u, 0u};
            if (y >= 0 && y < 64 && xg >= 0 && xg < 64)
                val = *(const uint4*)&in[((z * 64 + y) * 64 + xg) * 192 + ic0 + q * 8];
            *(uint4*)&Alds[(r * 66 + xx) * 40 + q * 8] = val;
        }
        __syncthreads();
#pragma unroll
        for (int tap = 0; tap < 9; ++tap) {
            int ky = tap / 3, kx = tap % 3;
            bf16x8 bfr[2];
#pragma unroll
            for (int fn = 0; fn < 2; ++fn) {
                int oc = oc0 + wn * 32 + fn * 16 + l15;
                bfr[fn] = *(const bf16x8*)&wt[(size_t)(tap * 192 + oc) * 192 + ic0 + 8 * lq];
            }
            int r = wm + ky;
#pragma unroll
            for (int g = 0; g < 4; ++g) {
                int xx = g * 16 + l15 + kx;
                bf16x8 afr = *(const bf16x8*)&Alds[(r * 66 + xx) * 40 + 8 * lq];
                acc[g][0] = __builtin_amdgcn_mfma_f32_16x16x32_bf16(afr, bfr[0], acc[g][0], 0, 0, 0);
                acc[g][1] = __builtin_amdgcn_mfma_f32_16x16x32_bf16(afr, bfr[1], acc[g][1], 0, 0, 0);
            }
        }
        __syncthreads();
    }
    int orow = y0 + wm;
#pragma unroll
    for (int g = 0; g < 4; ++g)
#pragma unroll
        for (int fn = 0; fn < 2; ++fn) {
            int oc = oc0 + wn * 32 + fn * 16 + l15;
            float ws = wsc[oc];
#pragma unroll
            for (int r2 = 0; r2 < 4; ++r2) {
                int px = g * 16 + lq * 4 + r2;
                float v = acc[g][fn][r2] * ws;
                v = mp_silu_f(v);
                out[((z * 64 + orow) * 64 + px) * 192 + oc] = f2bf(v);
            }
        }
}

// ---------------------------------------------------------------------------
// conv_out (slots, split-K): grid (16 tiles, 8 kchunks, 8 slots), atomicAdd.
__global__ __launch_bounds__(256) void conv_out_kernel(
    const unsigned short* __restrict__ in, const float* __restrict__ wbase,
    const float* __restrict__ wscb, const int* __restrict__ eidx,
    const float* __restrict__ gain, float* __restrict__ out) {
    int z = blockIdx.z, b = z >> 1;
    int e = eidx[z];
    float g = gain[z];
    const float* w = wbase + (size_t)e * 6912;
    const float* wsc = wscb + e * 4;
    int c0 = blockIdx.y * 24;
    int tileIdx = blockIdx.x;
    int ty0 = (tileIdx >> 2) * 16, tx0 = (tileIdx & 3) * 16;
    int lty = threadIdx.x >> 4, ltx = threadIdx.x & 15;
    int y = ty0 + lty, x = tx0 + ltx;
    __shared__ float tile[24][18][18];
    for (int i = threadIdx.x; i < 972; i += 256) {
        int q = i % 3, cell = i / 3;
        int rr = cell / 18, cc = cell % 18;
        int gy = ty0 - 1 + rr, gx = tx0 - 1 + cc;
        uint4 raw = {0u, 0u, 0u, 0u};
        if (gy >= 0 && gy < 64 && gx >= 0 && gx < 64)
            raw = *(const uint4*)&in[((z * 64 + gy) * 64 + gx) * 192 + c0 + q * 8];
        int icb = q * 8;
        tile[icb + 0][rr][cc] = bf2f((unsigned short)(raw.x & 0xffff));
        tile[icb + 1][rr][cc] = bf2f((unsigned short)(raw.x >> 16));
        tile[icb + 2][rr][cc] = bf2f((unsigned short)(raw.y & 0xffff));
        tile[icb + 3][rr][cc] = bf2f((unsigned short)(raw.y >> 16));
        tile[icb + 4][rr][cc] = bf2f((unsigned short)(raw.z & 0xffff));
        tile[icb + 5][rr][cc] = bf2f((unsigned short)(raw.z >> 16));
        tile[icb + 6][rr][cc] = bf2f((unsigned short)(raw.w & 0xffff));
        tile[icb + 7][rr][cc] = bf2f((unsigned short)(raw.w >> 16));
    }
    __syncthreads();
    float acc[4] = {0.f, 0.f, 0.f, 0.f};
#pragma unroll
    for (int ic = 0; ic < 24; ++ic) {
        float win[9];
#pragma unroll
        for (int ky = 0; ky < 3; ++ky)
#pragma unroll
            for (int kx = 0; kx < 3; ++kx)
                win[ky * 3 + kx] = tile[ic][lty + ky][ltx + kx];
#pragma unroll
        for (int o = 0; o < 4; ++o) {
            const float* wp = w + (size_t)(o * 192 + c0 + ic) * 9;
#pragma unroll
            for (int kk = 0; kk < 9; ++kk) acc[o] += wp[kk] * win[kk];
        }
    }
#pragma unroll
    for (int o = 0; o < 4; ++o)
        atomicAdd(&out[((b * 4 + o) * 64 + y) * 64 + x], g * acc[o] * wsc[o]);
}

// ---------------------------------------------------------------------------
// bf16 MFMA linear, expert-merged via gridDim.z (ViT stack).
template <int ACT>
__global__ __launch_bounds__(256) void mfma_linear_kernel(
    const float* __restrict__ A, int aE,
    const float* __restrict__ W, int wE,
    const float* __restrict__ wsc, int wscE,
    const float* __restrict__ pos, int posE,
    const float* __restrict__ cond, int condRow, int condE,
    const float* __restrict__ res, int resE, float outscale,
    const float* __restrict__ gate,
    float* __restrict__ out, int outE,
    int M, int N, int K) {
    int e = blockIdx.z;
    int bm = blockIdx.y * 32, bn = blockIdx.x * 64;
    if (gate && gate[(bm >> 6) * 4 + e] == 0.f) return;
    A += (size_t)e * aE;
    W += (size_t)e * wE;
    wsc += (size_t)e * wscE;
    if (pos) pos += (size_t)e * posE;
    if (cond) cond += (size_t)e * condE;
    if (res) res += (size_t)e * resE;
    out += (size_t)e * outE;

    int wid = threadIdx.x >> 6, lane = threadIdx.x & 63;
    int wm = wid >> 1, wn = wid & 1;
    int l15 = lane & 15, lq = lane >> 4;
    __shared__ unsigned short Alds[32 * 72];
    f32x4 acc[2];
    acc[0] = (f32x4){0.f, 0.f, 0.f, 0.f};
    acc[1] = (f32x4){0.f, 0.f, 0.f, 0.f};

    for (int k0 = 0; k0 < K; k0 += 64) {
#pragma unroll
        for (int p = 0; p < 2; ++p) {
            int i = threadIdx.x + p * 256;
            int row = i >> 4, kq = (i & 15) * 4;
            float4 va = *(const float4*)&A[(size_t)(bm + row) * K + k0 + kq];
            ushort4 sv;
            sv.x = f2bf(va.x); sv.y = f2bf(va.y); sv.z = f2bf(va.z); sv.w = f2bf(va.w);
            *(ushort4*)&Alds[row * 72 + kq] = sv;
        }
        __syncthreads();
#pragma unroll
        for (int ks = 0; ks < 2; ++ks) {
            bf16x8 afr = *(const bf16x8*)&Alds[(wm * 16 + l15) * 72 + ks * 32 + 8 * lq];
#pragma unroll
            for (int fn = 0; fn < 2; ++fn) {
                int n = bn + wn * 32 + fn * 16 + l15;
                const float* wp = &W[(size_t)n * K + k0 + ks * 32 + 8 * lq];
                float4 w0 = *(const float4*)wp;
                float4 w1 = *(const float4*)(wp + 4);
                bf16x8 bfr;
                bfr[0] = (short)f2bf(w0.x); bfr[1] = (short)f2bf(w0.y);
                bfr[2] = (short)f2bf(w0.z); bfr[3] = (short)f2bf(w0.w);
                bfr[4] = (short)f2bf(w1.x); bfr[5] = (short)f2bf(w1.y);
                bfr[6] = (short)f2bf(w1.z); bfr[7] = (short)f2bf(w1.w);
                acc[fn] = __builtin_amdgcn_mfma_f32_16x16x32_bf16(afr, bfr, acc[fn], 0, 0, 0);
            }
        }
        __syncthreads();
    }
#pragma unroll
    for (int fn = 0; fn < 2; ++fn) {
        int n = bn + wn * 32 + fn * 16 + l15;
        float ws = wsc[n];
#pragma unroll
        for (int r = 0; r < 4; ++r) {
            int m = bm + wm * 16 + lq * 4 + r;
            float val = acc[fn][r] * ws;
            if (pos) val += pos[(m & 63) * N + n];
            if (cond) val *= (1.f + cond[(m >> 6) * condRow + n]);
            if (ACT) val = mp_silu_f(val);
            if (res) val = (val + res[(size_t)m * N + n]) * outscale;
            out[(size_t)m * N + n] = val;
        }
    }
}

// ---- ViT self-attention over (e,b,h); float4 LDS reads
__global__ void vit_attn_kernel(const float* __restrict__ qkv_base,
                                const float* __restrict__ rwv,
                                float* __restrict__ out_base) {
    int e = blockIdx.x >> 5, b = (blockIdx.x >> 3) & 3, h = blockIdx.x & 7;
    if (rwv[b * 4 + e] == 0.f) return;
    const float* qkv = qkv_base + (size_t)e * 393216;
    float* out = out_base + (size_t)e * 131072;
    __shared__ float ks[64][68], vs[64][68], sc[64][65];
    int tid = threadIdx.x;
    for (int i = tid; i < 4096; i += 64) {
        int j = i >> 6, d = i & 63;
        ks[j][d] = qkv[(size_t)(b * 64 + j) * 1536 + 512 + h * 64 + d];
        vs[j][d] = qkv[(size_t)(b * 64 + j) * 1536 + 1024 + h * 64 + d];
    }
    float qreg[64];
#pragma unroll
    for (int d = 0; d < 64; ++d) qreg[d] = qkv[(size_t)(b * 64 + tid) * 1536 + h * 64 + d];
    __syncthreads();
    float mx = -1e30f;
    for (int j = 0; j < 64; ++j) {
        float s = 0.f;
#pragma unroll
        for (int d4 = 0; d4 < 16; ++d4) {
            float4 kk = *(const float4*)&ks[j][d4 * 4];
            s += qreg[d4 * 4] * kk.x + qreg[d4 * 4 + 1] * kk.y +
                 qreg[d4 * 4 + 2] * kk.z + qreg[d4 * 4 + 3] * kk.w;
        }
        s *= 0.125f;
        sc[tid][j] = s;
        mx = fmaxf(mx, s);
    }
    float sum = 0.f;
    for (int j = 0; j < 64; ++j) { float ee = __expf(sc[tid][j] - mx); sc[tid][j] = ee; sum += ee; }
    float inv = 1.f / sum;
    float4 acc4[16];
#pragma unroll
    for (int d4 = 0; d4 < 16; ++d4) acc4[d4] = (float4){0.f, 0.f, 0.f, 0.f};
    for (int j = 0; j < 64; ++j) {
        float ee = sc[tid][j];
#pragma unroll
        for (int d4 = 0; d4 < 16; ++d4) {
            float4 vv = *(const float4*)&vs[j][d4 * 4];
            acc4[d4].x += ee * vv.x; acc4[d4].y += ee * vv.y;
            acc4[d4].z += ee * vv.z; acc4[d4].w += ee * vv.w;
        }
    }
    float* op = &out[(size_t)(b * 64 + tid) * 512 + h * 64];
#pragma unroll
    for (int d4 = 0; d4 < 16; ++d4) {
        float4 r;
        r.x = acc4[d4].x * inv; r.y = acc4[d4].y * inv;
        r.z = acc4[d4].z * inv; r.w = acc4[d4].w * inv;
        *(float4*)&op[d4 * 4] = r;
    }
}

__global__ void unpatch_scatter_kernel(const float* __restrict__ vout,
                                       const float* __restrict__ rwv,
                                       float* __restrict__ out_vit) {
    int i = blockIdx.x * 256 + threadIdx.x;
    if (i >= 65536) return;
    int b = i >> 14;
    int c = (i >> 12) & 3, y = (i >> 6) & 63, x = i & 63;
    int f = c * 64 + (y & 7) * 8 + (x & 7);
    int s = (y >> 3) * 8 + (x >> 3);
    int idx = (b * 64 + s) * 256 + f;
    float acc = 0.f;
#pragma unroll
    for (int e = 0; e < 4; ++e) {
        float g = rwv[b * 4 + e];
        if (g != 0.f) acc += g * vout[e * 65536 + idx];
    }
    out_vit[i] = acc;
}

__global__ void ca_qkv_kernel(const float* __restrict__ ou, const float* __restrict__ ov,
                              const float* __restrict__ wq, const float* __restrict__ sq,
                              const float* __restrict__ wk, const float* __restrict__ sk,
                              const float* __restrict__ wv, const float* __restrict__ sv,
                              float* __restrict__ q, float* __restrict__ kx, float* __restrict__ vx) {
    int i = blockIdx.x * 256 + threadIdx.x;
    if (i >= 16384) return;
    int b = i >> 12, t = i & 4095;
    float u[4], c[4];
#pragma unroll
    for (int cc = 0; cc < 4; ++cc) {
        u[cc] = ou[(size_t)(b * 4 + cc) * 4096 + t];
        c[cc] = ov[(size_t)(b * 4 + cc) * 4096 + t];
    }
#pragma unroll
    for (int o = 0; o < 4; ++o) {
        float aq = 0.f, ak = 0.f, av = 0.f;
#pragma unroll
        for (int cc = 0; cc < 4; ++cc) {
            aq += wq[o * 4 + cc] * u[cc];
            ak += wk[o * 4 + cc] * c[cc];
            av += wv[o * 4 + cc] * c[cc];
        }
        q[(size_t)(b * 4096 + t) * 4 + o] = aq * sq[o];
        kx[(size_t)(b * 4096 + t) * 4 + o] = ak * sk[o];
        vx[(size_t)(b * 4096 + t) * 4 + o] = av * sv[o];
    }
}

// ---- cross-attn: 8 key-segments x 8-key ILP batches, LDS merge
__global__ __launch_bounds__(512) void ca_attn_kernel(
    const float* __restrict__ q, const float* __restrict__ k,
    const float* __restrict__ v, float* __restrict__ o) {
    int b = blockIdx.x >> 6;
    int lq = threadIdx.x & 63, seg = threadIdx.x >> 6;
    int qt = ((blockIdx.x & 63) << 6) + lq;
    float4 qv = *(const float4*)&q[(size_t)(b * 4096 + qt) * 4];
    const float4* kb = (const float4*)(k + (size_t)b * 16384);
    const float4* vb = (const float4*)(v + (size_t)b * 16384);
    float m = -1e30f, l = 0.f, a0 = 0.f, a1 = 0.f, a2 = 0.f, a3 = 0.f;
    int j0 = seg * 512;
    for (int j = j0; j < j0 + 512; j += 8) {
        float s[8];
#pragma unroll
        for (int u = 0; u < 8; ++u) {
            float4 kk = kb[j + u];
            s[u] = 0.5f * (qv.x * kk.x + qv.y * kk.y + qv.z * kk.z + qv.w * kk.w);
        }
        float bm = fmaxf(fmaxf(fmaxf(s[0], s[1]), fmaxf(s[2], s[3])),
                         fmaxf(fmaxf(s[4], s[5]), fmaxf(s[6], s[7])));
        float nm = fmaxf(m, bm);
        float corr = __expf(m - nm);
        l *= corr; a0 *= corr; a1 *= corr; a2 *= corr; a3 *= corr;
#pragma unroll
        for (int u = 0; u < 8; ++u) {
            float ee = __expf(s[u] - nm);
            float4 vv = vb[j + u];
            l += ee;
            a0 += ee * vv.x; a1 += ee * vv.y; a2 += ee * vv.z; a3 += ee * vv.w;
        }
        m = nm;
    }
    __shared__ float red[8][64][8];
    red[seg][lq][0] = m; red[seg][lq][1] = l;
    red[seg][lq][2] = a0; red[seg][lq][3] = a1;
    red[seg][lq][4] = a2; red[seg][lq][5] = a3;
    __syncthreads();
    if (seg == 0) {
#pragma unroll
        for (int s2 = 1; s2 < 8; ++s2) {
            float m2 = red[s2][lq][0], l2 = red[s2][lq][1];
            float nm = fmaxf(m, m2);
            float c1 = __expf(m - nm), c2 = __expf(m2 - nm);
            l = l * c1 + l2 * c2;
            a0 = a0 * c1 + red[s2][lq][2] * c2;
            a1 = a1 * c1 + red[s2][lq][3] * c2;
            a2 = a2 * c1 + red[s2][lq][4] * c2;
            a3 = a3 * c1 + red[s2][lq][5] * c2;
            m = nm;
        }
        float inv = 1.f / l;
        float* op = &o[(size_t)(b * 4096 + qt) * 4];
        op[0] = a0 * inv; op[1] = a1 * inv; op[2] = a2 * inv; op[3] = a3 * inv;
    }
}

// ---- fused: out-proj + balanced blend + gated combine -> d_out
__global__ void ca_final_kernel(const float* __restrict__ ao, const float* __restrict__ ou,
                                const float* __restrict__ wo, const float* __restrict__ so,
                                const float* __restrict__ gw1, const float* __restrict__ s1,
                                const float* __restrict__ gw2, const float* __restrict__ s2,
                                float* __restrict__ out) {
    int i = blockIdx.x * 256 + threadIdx.x;
    if (i >= 16384) return;
    int b = i >> 12, t = i & 4095;
    float oo[4], u[4], a[4];
#pragma unroll
    for (int j = 0; j < 4; ++j) oo[j] = ao[(size_t)(b * 4096 + t) * 4 + j];
#pragma unroll
    for (int c = 0; c < 4; ++c) u[c] = ou[(size_t)(b * 4 + c) * 4096 + t];
    const float binv = 1.21267812518f;  // 1/sqrt(0.2^2+0.8^2)
#pragma unroll
    for (int c = 0; c < 4; ++c) {
        float s = 0.f;
#pragma unroll
        for (int j = 0; j < 4; ++j) s += wo[c * 4 + j] * oo[j];
        s *= so[c];
        a[c] = (0.2f * u[c] + 0.8f * s) * binv;
    }
    float mvec[4];
#pragma unroll
    for (int o = 0; o < 4; ++o) {
        float s = 0.f;
#pragma unroll
        for (int c = 0; c < 4; ++c) s += gw1[o * 8 + c] * u[c] + gw1[o * 8 + 4 + c] * a[c];
        mvec[o] = mp_silu_f(s * s1[o]);
    }
    float g0 = 0.f, g1 = 0.f;
#pragma unroll
    for (int o = 0; o < 4; ++o) { g0 += gw2[o] * mvec[o]; g1 += gw2[4 + o] * mvec[o]; }
    g0 *= s2[0]; g1 *= s2[1];
    float mx = fmaxf(g0, g1);
    float e0 = expf(g0 - mx), e1 = expf(g1 - mx);
    float invd = 1.f / (e0 + e1);
    g0 = e0 * invd; g1 = e1 * invd;
#pragma unroll
    for (int c = 0; c < 4; ++c)
        out[(size_t)(b * 4 + c) * 4096 + t] = g0 * u[c] + g1 * a[c];
}

// ---------------------------------------------------------------------------
extern "C" void kernel_launch(void* const* d_in, const int* in_sizes, int n_in,
                              void* d_out, int out_size, void* d_ws, size_t ws_size,
                              hipStream_t stream) {
    (void)in_sizes; (void)n_in; (void)out_size; (void)ws_size;

    const float* x        = (const float*)d_in[0];
    const float* time_vec = (const float*)d_in[1];
    const float* text_emb = (const float*)d_in[2];
    const float* zeta     = (const float*)d_in[5];
    const float* f_freq   = (const float*)d_in[6];
    const float* f_phase  = (const float*)d_in[7];
    const float* w_f1     = (const float*)d_in[8];
    const float* w_f2     = (const float*)d_in[9];
    const float* w_scale  = (const float*)d_in[10];
    const float* w_ru     = (const float*)d_in[11];
    const float* w_rv     = (const float*)d_in[12];
    const float* uw_in    = (const float*)d_in[13];
    const float* uw_time  = (const float*)d_in[14];
    const float* uw_mid   = (const float*)d_in[15];
    const float* uw_out   = (const float*)d_in[16];
    const float* vw_patch = (const float*)d_in[17];
    const float* v_pos    = (const float*)d_in[18];
    const float* vw_qkv   = (const float*)d_in[19];
    const float* vw_proj  = (const float*)d_in[20];
    const float* vw_time  = (const float*)d_in[21];
    const float* vw_text  = (const float*)d_in[22];
    const float* vw_mlp1  = (const float*)d_in[23];
    const float* vw_mlp2  = (const float*)d_in[24];
    const float* vw_unp   = (const float*)d_in[25];
    const float* ca_wq    = (const float*)d_in[26];
    const float* ca_wk    = (const float*)d_in[27];
    const float* ca_wv    = (const float*)d_in[28];
    const float* ca_wo    = (const float*)d_in[29];
    const float* gw1      = (const float*)d_in[30];
    const float* gw2      = (const float*)d_in[31];

    float* out = (float*)d_out;

    float* Wp = (float*)d_ws;
    size_t off = 0;
    auto alloc = [&](size_t n) { float* p = Wp + off; off += (n + 3) & ~(size_t)3; return p; };

    float* s_wf1   = alloc(1024);
    float* s_wf2   = alloc(512);
    float* s_wsc   = alloc(2);
    float* s_wru   = alloc(4);
    float* s_wrv   = alloc(4);
    float* s_uwin  = alloc(768);
    float* s_uwt   = alloc(768);
    float* s_uwm   = alloc(768);
    float* s_uwo   = alloc(16);
    float* s_vwp   = alloc(2048);
    float* s_vwqkv = alloc(6144);
    float* s_vwpr  = alloc(2048);
    float* s_vwti  = alloc(2048);
    float* s_vwte  = alloc(2048);
    float* s_vwm1  = alloc(8192);
    float* s_vwm2  = alloc(2048);
    float* s_vwun  = alloc(1024);
    float* s_cawq  = alloc(4);
    float* s_cawk  = alloc(4);
    float* s_cawv  = alloc(4);
    float* s_cawo  = alloc(4);
    float* s_gw1   = alloc(4);
    float* s_gw2   = alloc(2);

    float* femb    = alloc(1024);
    float* h1      = alloc(4096);
    float* temb    = alloc(2048);
    float* scale2  = alloc(8);
    float* mean_x  = alloc(16);
    int*   eidx    = (int*)alloc(8);
    float* gain    = alloc(8);
    float* rwv     = alloc(16);
    float* textp   = alloc(3072);
    float* tvec    = alloc(3072);      // [4b][4e*192]
    float* patchtok= alloc(65536);
    float* in_unet = alloc(65536);
    float* in_vit  = alloc(65536);
    float* out_unet= alloc(65536);
    float* out_vit = alloc(65536);
    float* vcond   = alloc(8192);      // [4b][4e*512]
    unsigned short* wtmid = (unsigned short*)alloc(663552);   // [4e][9][192][192] bf16

    // union region: UNet slot buffers alias the ViT intermediates (the stream
    // fully serializes UNet convs before the ViT stack, so aliasing is safe).
    float* region  = alloc(6291456);
    unsigned short* bufA = (unsigned short*)region;                  // [8 slots][64][64][192] bf16
    unsigned short* bufB = (unsigned short*)(region + 3145728);
    float* vtok  = region + 0;         // [4e][256][512]
    float* vqkv  = region + 524288;    // [4e][256][1536]
    float* vao   = region + 2097152;   // [4e][256][512]
    float* vtok2 = region + 2621440;   // [4e][256][512]
    float* vhid  = region + 3145728;   // [4e][256][2048]
    float* vtok3 = region + 5242880;   // [4e][256][512]
    float* vout  = region + 5767168;   // [4e][256][256]

    float* caq     = alloc(65536);
    float* cak     = alloc(65536);
    float* cav     = alloc(65536);
    float* cao     = alloc(65536);

    // ---- merged rowscale
    RsTab tab;
    int rowCounts[23] = {1024, 512, 2, 4, 4, 768, 768, 768, 16, 2048, 6144, 2048,
                         2048, 2048, 8192, 2048, 1024, 4, 4, 4, 4, 4, 2};
    const float* srcs[23] = {w_f1, w_f2, w_scale, w_ru, w_rv, uw_in, uw_time, uw_mid, uw_out,
                             vw_patch, vw_qkv, vw_proj, vw_time, vw_text, vw_mlp1, vw_mlp2,
                             vw_unp, ca_wq, ca_wk, ca_wv, ca_wo, gw1, gw2};
    float* dsts[23] = {s_wf1, s_wf2, s_wsc, s_wru, s_wrv, s_uwin, s_uwt, s_uwm, s_uwo,
                       s_vwp, s_vwqkv, s_vwpr, s_vwti, s_vwte, s_vwm1, s_vwm2,
                       s_vwun, s_cawq, s_cawk, s_cawv, s_cawo, s_gw1, s_gw2};
    int fans[23] = {256, 1024, 512, 516, 516, 36, 512, 1728, 1728, 256, 512, 512,
                    512, 768, 512, 2048, 512, 4, 4, 4, 4, 8, 4};
    int cum = 0;
    for (int i = 0; i < 23; ++i) {
        tab.e[i].w = srcs[i]; tab.e[i].o = dsts[i];
        tab.e[i].fan = fans[i]; tab.e[i].rowStart = cum;
        cum += rowCounts[i];
    }
    rowscale_all_kernel<<<dim3(cum), dim3(256), 0, stream>>>(tab);
    wmid_cvt_kernel<<<dim3((1327104 + 255) / 256), dim3(256), 0, stream>>>(uw_mid, wtmid);

    auto gemv = [&](int ACT, int HASRES, const float* A, const float* W2, const float* wsc,
                    const float* res, float osc, float* o, int M, int N, int K) {
        dim3 g(M * N / 4);
        if (ACT)
            gemv_kernel<1, 0><<<g, 256, 0, stream>>>(A, W2, wsc, res, osc, o, N, K);
        else if (HASRES)
            gemv_kernel<0, 1><<<g, 256, 0, stream>>>(A, W2, wsc, res, osc, o, N, K);
        else
            gemv_kernel<0, 0><<<g, 256, 0, stream>>>(A, W2, wsc, res, osc, o, N, K);
    };

    // ---- time embedding chain
    femb_kernel<<<dim3(4), dim3(256), 0, stream>>>(time_vec, f_freq, f_phase, femb);
    gemv(1, 0, femb, w_f1, s_wf1, nullptr, 1.f, h1, 4, 1024, 256);
    gemv(0, 0, h1, w_f2, s_wf2, nullptr, 1.f, temb, 4, 512, 1024);

    scale_kernel<<<dim3(1), dim3(64), 0, stream>>>(temb, w_scale, s_wsc, zeta, scale2);
    meanx_kernel<<<dim3(16), dim3(256), 0, stream>>>(x, mean_x);
    router_kernel<<<dim3(1), dim3(64), 0, stream>>>(mean_x, scale2, temb, w_ru, s_wru, w_rv, s_wrv,
                                                    zeta, eidx, gain, rwv, out + 65536);
    make_inputs_kernel<<<dim3(256), dim3(256), 0, stream>>>(x, scale2, in_vit, in_unet);
    textp_kernel<<<dim3(12), dim3(256), 0, stream>>>(text_emb, textp);
    patchify_kernel<<<dim3(256), dim3(256), 0, stream>>>(in_vit, patchtok);

    // per-expert UNet time mod: tvec [4b][4e*192]
    gemv(0, 0, temb, uw_time, s_uwt, nullptr, 1.f, tvec, 4, 768, 512);

    hipMemsetAsync(out_unet, 0, 65536 * sizeof(float), stream);

    // ---- UNet conv chain, slot-compacted (one dispatch per stage)
    conv_in_kernel<<<dim3(16, 24, 8), dim3(256), 0, stream>>>(
        in_unet, uw_in, s_uwin, tvec, eidx, bufA);
    conv_mid_mfma<<<dim3(32, 3, 8), dim3(256), 0, stream>>>(
        bufA, wtmid, s_uwm, eidx, bufB);
    conv_out_kernel<<<dim3(16, 8, 8), dim3(256), 0, stream>>>(
        bufB, uw_out, s_uwo, eidx, gain, out_unet);

    // ---- ViT cond vectors: vcond [4b][4e*512]
    gemv(0, 0, temb, vw_time, s_vwti, nullptr, 1.f, vcond, 4, 2048, 512);
    gemv(0, 1, textp, vw_text, s_vwte, vcond, 1.f, vcond, 4, 2048, 768);

    auto mlin = [&](int ACT, const float* A, int aE, const float* W2, int wE2,
                    const float* wsc, int wscE, const float* pos, int posE,
                    const float* cond, int condRow, int condE,
                    const float* res, int resE, float osc,
                    const float* gate, float* o, int outE, int M, int N, int K) {
        dim3 g(N / 64, M / 32, 4);
        if (ACT)
            mfma_linear_kernel<1><<<g, 256, 0, stream>>>(A, aE, W2, wE2, wsc, wscE, pos, posE,
                                                         cond, condRow, condE, res, resE, osc,
                                                         gate, o, outE, M, N, K);
        else
            mfma_linear_kernel<0><<<g, 256, 0, stream>>>(A, aE, W2, wE2, wsc, wscE, pos, posE,
                                                         cond, condRow, condE, res, resE, osc,
                                                         gate, o, outE, M, N, K);
    };

    // ---- ViT expert stack
    mlin(0, patchtok, 0, vw_patch, 131072, s_vwp, 512, v_pos, 32768,
         vcond, 2048, 512, nullptr, 0, 1.f, rwv, vtok, 131072, 256, 512, 256);
    mlin(0, vtok, 131072, vw_qkv, 786432, s_vwqkv, 1536, nullptr, 0,
         nullptr, 0, 0, nullptr, 0, 1.f, rwv, vqkv, 393216, 256, 1536, 512);
    vit_attn_kernel<<<dim3(128), dim3(64), 0, stream>>>(vqkv, rwv, vao);
    mlin(0, vao, 131072, vw_proj, 262144, s_vwpr, 512, nullptr, 0,
         nullptr, 0, 0, vtok, 131072, 0.70710678f, rwv, vtok2, 131072, 256, 512, 512);
    mlin(1, vtok2, 131072, vw_mlp1, 1048576, s_vwm1, 2048, nullptr, 0,
         nullptr, 0, 0, nullptr, 0, 1.f, rwv, vhid, 524288, 256, 2048, 512);
    mlin(0, vhid, 524288, vw_mlp2, 1048576, s_vwm2, 512, nullptr, 0,
         nullptr, 0, 0, vtok2, 131072, 0.70710678f, rwv, vtok3, 131072, 256, 512, 2048);
    mlin(0, vtok3, 131072, vw_unp, 131072, s_vwun, 256, nullptr, 0,
         nullptr, 0, 0, nullptr, 0, 1.f, rwv, vout, 65536, 256, 256, 512);
    unpatch_scatter_kernel<<<dim3(256), dim3(256), 0, stream>>>(vout, rwv, out_vit);

    // ---- cross attention + fused tail
    ca_qkv_kernel<<<dim3(64), dim3(256), 0, stream>>>(out_unet, out_vit, ca_wq, s_cawq,
                                                      ca_wk, s_cawk, ca_wv, s_cawv, caq, cak, cav);
    ca_attn_kernel<<<dim3(256), dim3(512), 0, stream>>>(caq, cak, cav, cao);
    ca_final_kernel<<<dim3(64), dim3(256), 0, stream>>>(cao, out_unet, ca_wo, s_cawo,
                                                        gw1, s_gw1, gw2, s_gw2, out);
}